// Round 4
// baseline (7484.274 us; speedup 1.0000x reference)
//
#include <hip/hip_runtime.h>
#include <hip/hip_bf16.h>
#include <math.h>

typedef __hip_bfloat16 bf16;

#define AMODE_PLAIN  0
#define AMODE_LATIN  1
#define AMODE_CONCAT 2
#define EPI_SILU     0
#define EPI_FCUT     1
#define EPI_ENVSPLIT 2
#define EPI_RESID    3
#define EPI_ENV1     4
#define EPI_FINAL    5

#define INV_SQRT_N 0.17677669529663687f   /* 1/sqrt(32) */
#define INV_SQRT3  0.5773502691896258f
#define INV_SQRT2  0.7071067811865476f
#define C_OLD      0.8944271909999159f    /* 1/sqrt(1.25) */
#define C_NEW      0.4472135954999579f
#define PI_F       3.14159265358979323846f
#define SQRT3_F    1.7320508075688772f
#define BESSEL_PREF 0.6324555320336759f   /* sqrt(2/5) */

__device__ __forceinline__ float b2f(bf16 x) { return __bfloat162float(x); }
__device__ __forceinline__ bf16  f2b(float x) { return __float2bfloat16(x); }
__device__ __forceinline__ void atomAddF(float* p, float v) { atomicAdd(p, v); }
__device__ __forceinline__ float silu_f(float v) { return v / (1.f + __expf(-v)); }

// ---------------------------------------------------------------------------
// per-edge geometry: fcut, Y (1, sqrt3*unit) [fp32], edge_feats [bf16]
// ---------------------------------------------------------------------------
__global__ __launch_bounds__(256) void k_geom(
    const float* __restrict__ coords, const int* __restrict__ eidx, int E,
    float* __restrict__ fcut, float* __restrict__ Yb, bf16* __restrict__ ef) {
  int e = blockIdx.x * 256 + threadIdx.x;
  if (e >= E) return;
  int s = eidx[e], c = eidx[E + e];
  float dx = coords[c*3+0] - coords[s*3+0];
  float dy = coords[c*3+1] - coords[s*3+1];
  float dz = coords[c*3+2] - coords[s*3+2];
  float r = sqrtf(dx*dx + dy*dy + dz*dz + 1e-12f);
  float u = r * 0.2f;
  float u3 = u*u*u;
  float u6 = u3*u3, u7 = u6*u, u8 = u7*u;
  float fc = 1.f - 28.f*u6 + 48.f*u7 - 21.f*u8;
  fc = (u < 1.f) ? fc : 0.f;
  float inv_r = 1.f / r;
  fcut[e] = fc;
  Yb[e*4+0] = 1.f;
  Yb[e*4+1] = SQRT3_F * dx * inv_r;
  Yb[e*4+2] = SQRT3_F * dy * inv_r;
  Yb[e*4+3] = SQRT3_F * dz * inv_r;
  float pref = BESSEL_PREF * inv_r * fc;
  #pragma unroll
  for (int n = 1; n <= 8; ++n)
    ef[e*8 + n - 1] = f2b(pref * sinf((float)n * PI_F * u));
}

// ---------------------------------------------------------------------------
// Tiled fp32-compute GEMM over edges: 64 edges x NOUT per block, 256 threads.
// A inputs: bf16 internal buffers (or fp32 nattr for LATIN); W: fp32 input.
// ---------------------------------------------------------------------------
template<int K, int KC, int NOUT, int AMODE, int EPI>
__global__ __launch_bounds__(256) void gemm_k(
    const bf16* __restrict__ A, const bf16* __restrict__ A2,
    const float* __restrict__ W, bf16* __restrict__ outb,
    const int* __restrict__ eidx, const float* __restrict__ nattr,
    const float* __restrict__ fcut, const float* __restrict__ Yb,
    float* __restrict__ env, float scale, int E) {
  constexpr int BM = 64;
  constexpr int BMP = BM + 1;
  constexpr int TN = NOUT / 16;
  __shared__ __align__(16) float As[KC * BMP];   // [k][e]
  __shared__ __align__(16) float Bs[KC * NOUT];  // [k][j]

  int tid = threadIdx.x;
  int tx = tid & 15, ty = tid >> 4;
  long e0 = (long)blockIdx.x * BM;
  float acc[4][TN];
  #pragma unroll
  for (int mm = 0; mm < 4; ++mm)
    #pragma unroll
    for (int nn = 0; nn < TN; ++nn) acc[mm][nn] = 0.f;

  for (int k0 = 0; k0 < K; k0 += KC) {
    for (int i = tid; i < BM * KC; i += 256) {
      int e = i / KC, k = i % KC;
      long eg = e0 + e;
      int kk = k0 + k;
      float v = 0.f;
      if (eg < E) {
        if constexpr (AMODE == AMODE_PLAIN) {
          v = b2f(A[eg * K + kk]);
        } else if constexpr (AMODE == AMODE_LATIN) {
          if (kk < 16)       { int c = eidx[E + eg]; v = nattr[(long)c*16 + kk]; }
          else if (kk < 32)  { int s = eidx[eg];     v = nattr[(long)s*16 + kk - 16]; }
          else               { v = b2f(A2[eg*8 + kk - 32]); }
        } else {
          v = (kk < 128) ? b2f(A[eg*128 + kk]) : b2f(A2[eg*64 + (kk - 128)]);
        }
      }
      As[k * BMP + e] = v;
    }
    for (int i = tid; i < KC * NOUT; i += 256) {
      int k = i / NOUT, j = i % NOUT;
      Bs[i] = W[(long)(k0 + k) * NOUT + j];
    }
    __syncthreads();
    #pragma unroll
    for (int k = 0; k < KC; ++k) {
      float a[4];
      #pragma unroll
      for (int mm = 0; mm < 4; ++mm) a[mm] = As[k * BMP + ty*4 + mm];
      float b[TN];
      #pragma unroll
      for (int nn = 0; nn < TN; nn += 4) {
        float4 t = *reinterpret_cast<const float4*>(&Bs[k * NOUT + tx*TN + nn]);
        b[nn] = t.x; b[nn+1] = t.y; b[nn+2] = t.z; b[nn+3] = t.w;
      }
      #pragma unroll
      for (int mm = 0; mm < 4; ++mm)
        #pragma unroll
        for (int nn = 0; nn < TN; ++nn)
          acc[mm][nn] = fmaf(a[mm], b[nn], acc[mm][nn]);
    }
    __syncthreads();
  }

  #pragma unroll
  for (int mm = 0; mm < 4; ++mm) {
    long eg = e0 + ty*4 + mm;
    if (eg >= E) continue;
    if constexpr (EPI == EPI_SILU) {
      #pragma unroll
      for (int nn = 0; nn < TN; ++nn)
        outb[eg * NOUT + tx*TN + nn] = f2b(silu_f(acc[mm][nn] * scale));
    } else if constexpr (EPI == EPI_ENVSPLIT) {
      if (tx < 8) {
        #pragma unroll
        for (int nn = 0; nn < TN; ++nn)
          outb[eg * 64 + tx*TN + nn] = f2b(acc[mm][nn] * scale);
      } else {
        int c = eidx[E + eg];
        float y1 = Yb[eg*4+1], y2 = Yb[eg*4+2], y3 = Yb[eg*4+3];
        float* base = env + (long)c * 128;
        #pragma unroll
        for (int nn = 0; nn < TN; nn += 2) {
          int jj = tx*TN + nn - 64;
          int mi = jj >> 1;
          float w0 = acc[mm][nn]   * scale;
          float w1 = acc[mm][nn+1] * scale;
          atomAddF(base + mi*4 + 0, w0);
          atomAddF(base + mi*4 + 1, w1 * y1);
          atomAddF(base + mi*4 + 2, w1 * y2);
          atomAddF(base + mi*4 + 3, w1 * y3);
        }
      }
    } else if constexpr (EPI == EPI_ENV1) {
      int c = eidx[E + eg];
      float y1 = Yb[eg*4+1], y2 = Yb[eg*4+2], y3 = Yb[eg*4+3];
      float* base = env + (long)c * 128;
      #pragma unroll
      for (int nn = 0; nn < TN; nn += 2) {
        int jj = tx*TN + nn;
        int mi = jj >> 1;
        float w0 = acc[mm][nn]   * scale;
        float w1 = acc[mm][nn+1] * scale;
        atomAddF(base + mi*4 + 0, w0);
        atomAddF(base + mi*4 + 1, w1 * y1);
        atomAddF(base + mi*4 + 2, w1 * y2);
        atomAddF(base + mi*4 + 3, w1 * y3);
      }
    }
  }
}

// ---------------------------------------------------------------------------
// Fused two-layer MLP: A(K) -> silu(@W0) hidden 128 in LDS -> @W1 -> epilogue.
// ---------------------------------------------------------------------------
template<int K, int KC, int AMODE, int EPI>
__global__ __launch_bounds__(256) void fused2_k(
    const bf16* __restrict__ A, const bf16* __restrict__ A2,
    const float* __restrict__ W0, const float* __restrict__ W1,
    bf16* __restrict__ outb, float* __restrict__ outf,
    const int* __restrict__ eidx, const float* __restrict__ fcut,
    const bf16* __restrict__ lat_old,
    float scale0, float scale1, int E) {
  constexpr int BM = 64;
  constexpr int BMP = BM + 1;
  __shared__ __align__(16) float As[KC * BMP];
  __shared__ __align__(16) float Bs[KC * 128];
  __shared__ __align__(16) float Hs[128 * BMP];

  int tid = threadIdx.x;
  int tx = tid & 15, ty = tid >> 4;
  long e0 = (long)blockIdx.x * BM;
  float acc[4][8];
  #pragma unroll
  for (int mm = 0; mm < 4; ++mm)
    #pragma unroll
    for (int nn = 0; nn < 8; ++nn) acc[mm][nn] = 0.f;

  for (int k0 = 0; k0 < K; k0 += KC) {
    for (int i = tid; i < BM * KC; i += 256) {
      int e = i / KC, k = i % KC;
      long eg = e0 + e;
      int kk = k0 + k;
      float v = 0.f;
      if (eg < E) {
        if constexpr (AMODE == AMODE_PLAIN) {
          v = b2f(A[eg * K + kk]);
        } else {
          v = (kk < 128) ? b2f(A[eg*128 + kk]) : b2f(A2[eg*64 + (kk - 128)]);
        }
      }
      As[k * BMP + e] = v;
    }
    for (int i = tid; i < KC * 128; i += 256) {
      int k = i / 128, j = i % 128;
      Bs[i] = W0[(long)(k0 + k) * 128 + j];
    }
    __syncthreads();
    #pragma unroll
    for (int k = 0; k < KC; ++k) {
      float a[4];
      #pragma unroll
      for (int mm = 0; mm < 4; ++mm) a[mm] = As[k * BMP + ty*4 + mm];
      float b[8];
      #pragma unroll
      for (int nn = 0; nn < 8; nn += 4) {
        float4 t = *reinterpret_cast<const float4*>(&Bs[k * 128 + tx*8 + nn]);
        b[nn] = t.x; b[nn+1] = t.y; b[nn+2] = t.z; b[nn+3] = t.w;
      }
      #pragma unroll
      for (int mm = 0; mm < 4; ++mm)
        #pragma unroll
        for (int nn = 0; nn < 8; ++nn)
          acc[mm][nn] = fmaf(a[mm], b[nn], acc[mm][nn]);
    }
    __syncthreads();
  }
  #pragma unroll
  for (int mm = 0; mm < 4; ++mm)
    #pragma unroll
    for (int nn = 0; nn < 8; ++nn)
      Hs[(tx*8 + nn) * BMP + (ty*4 + mm)] = silu_f(acc[mm][nn] * scale0);

  #pragma unroll
  for (int mm = 0; mm < 4; ++mm)
    #pragma unroll
    for (int nn = 0; nn < 8; ++nn) acc[mm][nn] = 0.f;

  for (int k0 = 0; k0 < 128; k0 += KC) {
    __syncthreads();
    for (int i = tid; i < KC * 128; i += 256) {
      int k = i / 128, j = i % 128;
      Bs[i] = W1[(long)(k0 + k) * 128 + j];
    }
    __syncthreads();
    #pragma unroll
    for (int k = 0; k < KC; ++k) {
      float a[4];
      #pragma unroll
      for (int mm = 0; mm < 4; ++mm) a[mm] = Hs[(k0 + k) * BMP + ty*4 + mm];
      float b[8];
      #pragma unroll
      for (int nn = 0; nn < 8; nn += 4) {
        float4 t = *reinterpret_cast<const float4*>(&Bs[k * 128 + tx*8 + nn]);
        b[nn] = t.x; b[nn+1] = t.y; b[nn+2] = t.z; b[nn+3] = t.w;
      }
      #pragma unroll
      for (int mm = 0; mm < 4; ++mm)
        #pragma unroll
        for (int nn = 0; nn < 8; ++nn)
          acc[mm][nn] = fmaf(a[mm], b[nn], acc[mm][nn]);
    }
  }

  #pragma unroll
  for (int mm = 0; mm < 4; ++mm) {
    long eg = e0 + ty*4 + mm;
    if (eg >= E) continue;
    float fc = fcut[eg];
    if constexpr (EPI == EPI_FCUT) {
      #pragma unroll
      for (int nn = 0; nn < 8; ++nn)
        outb[eg * 128 + tx*8 + nn] = f2b(acc[mm][nn] * scale1 * fc);
    } else if constexpr (EPI == EPI_RESID) {
      #pragma unroll
      for (int nn = 0; nn < 8; ++nn) {
        long idx = eg * 128 + tx*8 + nn;
        float v = acc[mm][nn] * scale1 * fc;
        outb[idx] = f2b(C_OLD * b2f(outb[idx]) + C_NEW * v);
      }
    } else { // EPI_FINAL: accumulate node output directly into fp32 d_out
      int c = eidx[E + eg];
      #pragma unroll
      for (int nn = 0; nn < 8; ++nn) {
        int j = tx*8 + nn;
        float v = acc[mm][nn] * scale1 * fc;
        float lf = C_OLD * b2f(lat_old[eg*128 + j]) + C_NEW * v;
        atomAddF(outf + (long)c*128 + j, lf * INV_SQRT_N);
      }
    }
  }
}

// ---------------------------------------------------------------------------
__global__ __launch_bounds__(256) void k_prod(
    const bf16* __restrict__ wedge, const float* __restrict__ env,
    const float* __restrict__ Yb, const int* __restrict__ eidx, int E,
    bf16* __restrict__ scal) {
  long t = (long)blockIdx.x * 256 + threadIdx.x;
  if (t >= (long)E * 32) return;
  long e = t >> 5;
  int m = (int)(t & 31);
  int c = eidx[E + e];
  float w0 = b2f(wedge[e*64 + 2*m]), w1 = b2f(wedge[e*64 + 2*m + 1]);
  const float* ep = env + (long)c*128 + m*4;
  float es  = ep[0] * INV_SQRT_N;
  float evx = ep[1] * INV_SQRT_N, evy = ep[2] * INV_SQRT_N, evz = ep[3] * INV_SQRT_N;
  float y1 = Yb[e*4+1], y2 = Yb[e*4+2], y3 = Yb[e*4+3];
  float fvx = w1*y1, fvy = w1*y2, fvz = w1*y3;
  scal[e*64 + m]      = f2b(w0 * es);
  scal[e*64 + 32 + m] = f2b((fvx*evx + fvy*evy + fvz*evz) * INV_SQRT3);
}

// ---------------------------------------------------------------------------
#define MIX_TE 8
__global__ __launch_bounds__(256) void k_mix(
    const bf16* __restrict__ wedge, const float* __restrict__ env,
    const float* __restrict__ env1, const float* __restrict__ Yb,
    const int* __restrict__ eidx, int E,
    const float* __restrict__ Ws0, const float* __restrict__ Wv0,
    bf16* __restrict__ scal) {
  __shared__ float P[MIX_TE * 32 * 13];
  __shared__ float E1s[MIX_TE * 32 * 5];
  __shared__ float WS[64 * 32];
  __shared__ float WV[96 * 32];
  int tid = threadIdx.x;
  for (int i = tid; i < 64*32; i += 256) WS[i] = Ws0[i];
  for (int i = tid; i < 96*32; i += 256) WV[i] = Wv0[i];
  int el = tid >> 5, m = tid & 31;
  long e = (long)blockIdx.x * MIX_TE + el;
  bool valid = (e < E);
  if (valid) {
    int c = eidx[E + e];
    float w0 = b2f(wedge[e*64 + 2*m]), w1 = b2f(wedge[e*64 + 2*m + 1]);
    const float* ep = env + (long)c*128 + m*4;
    float es  = ep[0] * INV_SQRT_N;
    float evx = ep[1] * INV_SQRT_N, evy = ep[2] * INV_SQRT_N, evz = ep[3] * INV_SQRT_N;
    float y1 = Yb[e*4+1], y2 = Yb[e*4+2], y3 = Yb[e*4+3];
    float fvx = w1*y1, fvy = w1*y2, fvz = w1*y3;
    float* p = &P[(el*32 + m) * 13];
    p[0]  = w0 * es;
    p[1]  = (fvx*evx + fvy*evy + fvz*evz) * INV_SQRT3;
    p[2]  = w0 * evx; p[3] = w0 * evy; p[4] = w0 * evz;
    p[5]  = fvx * es; p[6] = fvy * es; p[7] = fvz * es;
    p[8]  = (fvy*evz - fvz*evy) * INV_SQRT2;
    p[9]  = (fvz*evx - fvx*evz) * INV_SQRT2;
    p[10] = (fvx*evy - fvy*evx) * INV_SQRT2;
    const float* e1p = env1 + (long)c*128 + m*4;
    float* qd = &E1s[(el*32 + m) * 5];
    qd[0] = e1p[0]*INV_SQRT_N; qd[1] = e1p[1]*INV_SQRT_N;
    qd[2] = e1p[2]*INV_SQRT_N; qd[3] = e1p[3]*INV_SQRT_N;
  }
  __syncthreads();
  if (!valid) return;
  int o = m;
  float s = 0.f, v0 = 0.f, v1 = 0.f, v2 = 0.f;
  for (int mm = 0; mm < 32; ++mm) {
    const float* pp = &P[(el*32 + mm) * 13];
    float ws0 = WS[mm*32 + o], ws1 = WS[(32+mm)*32 + o];
    s = fmaf(pp[0], ws0, s); s = fmaf(pp[1], ws1, s);
    float wa = WV[mm*32 + o], wb = WV[(32+mm)*32 + o], wc = WV[(64+mm)*32 + o];
    v0 = fmaf(pp[2], wa, v0); v0 = fmaf(pp[5], wb, v0); v0 = fmaf(pp[8],  wc, v0);
    v1 = fmaf(pp[3], wa, v1); v1 = fmaf(pp[6], wb, v1); v1 = fmaf(pp[9],  wc, v1);
    v2 = fmaf(pp[4], wa, v2); v2 = fmaf(pp[7], wb, v2); v2 = fmaf(pp[10], wc, v2);
  }
  s  *= 0.125f;
  v0 *= 0.10206207261596577f;
  v1 *= 0.10206207261596577f;
  v2 *= 0.10206207261596577f;
  const float* qv = &E1s[(el*32 + o) * 5];
  float q0 = s * qv[0];
  float q1 = (v0*qv[1] + v1*qv[2] + v2*qv[3]) * INV_SQRT3;
  scal[e*64 + o]      = f2b(q0);
  scal[e*64 + 32 + o] = f2b(q1);
}

// ---------------------------------------------------------------------------
extern "C" void kernel_launch(void* const* d_in, const int* in_sizes, int n_in,
                              void* d_out, int out_size, void* d_ws, size_t ws_size,
                              hipStream_t stream) {
  const float* coords = (const float*)d_in[0];
  const float* nattr  = (const float*)d_in[1];
  const int*   eidx   = (const int*)d_in[2];
  const float* W2b0   = (const float*)d_in[3];
  const float* W2b1   = (const float*)d_in[4];
  const float* W2b2   = (const float*)d_in[5];
  const float* Wenv0  = (const float*)d_in[6];
  const float* Wlat0  = (const float*)d_in[7];
  const float* Wlat1  = (const float*)d_in[8];
  const float* Ws0    = (const float*)d_in[9];
  const float* Wv0    = (const float*)d_in[10];
  const float* Wenv1  = (const float*)d_in[11];
  const float* Wfin0  = (const float*)d_in[12];
  const float* Wfin1  = (const float*)d_in[13];
  float* out = (float*)d_out;
  int E = in_sizes[2] / 2;     // 320000
  int N = in_sizes[0] / 3;     // 10000

  // workspace carve: fp32 regions then bf16 regions.  ~181 MB total.
  float* fcut = (float*)d_ws;                     // E
  float* Yb   = fcut + (size_t)E;                 // 4E
  float* env  = Yb + (size_t)E*4;                 // 128N
  float* env1 = env + (size_t)N*128;              // 128N
  bf16*  b64  = (bf16*)(env1 + (size_t)N*128);    // 64E  (h64, then w_edge)
  bf16*  lat  = b64 + (size_t)E*64;               // 128E
  bf16*  scal = lat + (size_t)E*128;              // 64E  (ef first 8E, then scal0/1)
  bf16*  ef   = scal;

  hipMemsetAsync(env,  0, (size_t)N * 128 * sizeof(float), stream);
  hipMemsetAsync(env1, 0, (size_t)N * 128 * sizeof(float), stream);
  hipMemsetAsync(out,  0, (size_t)N * 128 * sizeof(float), stream);

  dim3 blk(256);
  const float s40  = 0.15811388300841897f;  // 1/sqrt(40)
  const float s64  = 0.125f;
  const float s128 = 0.08838834764831845f;
  const float s192 = 0.07216878364870323f;
  int gB = (E + 63) / 64;

  k_geom<<<dim3((E + 255) / 256), blk, 0, stream>>>(coords, eidx, E, fcut, Yb, ef);

  // two-body MLP: 40 -> 64 (silu) -> fused [64 -> 128 silu -> 128] * fcut -> lat
  gemm_k<40,40,64,AMODE_LATIN,EPI_SILU><<<gB, blk, 0, stream>>>(
      nullptr, ef, W2b0, b64, eidx, nattr, fcut, Yb, nullptr, s40, E);
  fused2_k<64,32,AMODE_PLAIN,EPI_FCUT><<<gB, blk, 0, stream>>>(
      b64, nullptr, W2b1, W2b2, lat, nullptr, eidx, fcut, nullptr, s64, s128, E);

  // Wenv0: w_edge -> b64, w_env -> env atomics
  gemm_k<128,32,128,AMODE_PLAIN,EPI_ENVSPLIT><<<gB, blk, 0, stream>>>(
      lat, nullptr, Wenv0, b64, eidx, nattr, fcut, Yb, env, s128, E);

  // products -> scal0
  k_prod<<<dim3((int)(((long)E*32 + 255) / 256)), blk, 0, stream>>>(
      b64, env, Yb, eidx, E, scal);

  // latent MLP (fused 192 -> 128 silu -> 128) * fcut, residual into lat
  fused2_k<192,32,AMODE_CONCAT,EPI_RESID><<<gB, blk, 0, stream>>>(
      lat, scal, Wlat0, Wlat1, lat, nullptr, eidx, fcut, nullptr, s192, s128, E);

  // Wenv1 -> env1 atomics
  gemm_k<128,32,64,AMODE_PLAIN,EPI_ENV1><<<gB, blk, 0, stream>>>(
      lat, nullptr, Wenv1, nullptr, eidx, nattr, fcut, Yb, env1, s128, E);

  // mix -> scal1
  k_mix<<<dim3((E + MIX_TE - 1) / MIX_TE), blk, 0, stream>>>(
      b64, env, env1, Yb, eidx, E, Ws0, Wv0, scal);

  // final MLP (fused) + residual + node segment-sum directly into fp32 d_out
  fused2_k<192,32,AMODE_CONCAT,EPI_FINAL><<<gB, blk, 0, stream>>>(
      lat, scal, Wfin0, Wfin1, nullptr, out, eidx, fcut, lat, s192, s128, E);
}

// Round 5
// 7374.150 us; speedup vs baseline: 1.0149x; 1.0149x over previous
//
#include <hip/hip_runtime.h>
#include <hip/hip_bf16.h>
#include <math.h>

typedef __hip_bfloat16 bf16;

#define AMODE_PLAIN  0
#define AMODE_LATIN  1
#define AMODE_CONCAT 2
#define EPI_SILU     0
#define EPI_FCUT     1
#define EPI_ENVSPLIT 2
#define EPI_RESID    3
#define EPI_ENV1     4
#define EPI_FINAL    5

#define INV_SQRT_N 0.17677669529663687f   /* 1/sqrt(32) */
#define INV_SQRT3  0.5773502691896258f
#define INV_SQRT2  0.7071067811865476f
#define C_OLD      0.8944271909999159f    /* 1/sqrt(1.25) */
#define C_NEW      0.4472135954999579f
#define PI_F       3.14159265358979323846f
#define SQRT3_F    1.7320508075688772f
#define BESSEL_PREF 0.6324555320336759f   /* sqrt(2/5) */

__device__ __forceinline__ float b2f(bf16 x) { return __bfloat162float(x); }
__device__ __forceinline__ bf16  f2b(float x) { return __float2bfloat16(x); }
// d_ws is coarse-grained device memory: native global_atomic_add_f32 is safe
// there. (Safe atomicAdd = CAS loop on gfx950 -> 1.32 GB writes/dispatch, the
// round-4 bottleneck.)
__device__ __forceinline__ void atomAddF(float* p, float v) { unsafeAtomicAdd(p, v); }
__device__ __forceinline__ float silu_f(float v) { return v / (1.f + __expf(-v)); }

// ---------------------------------------------------------------------------
// per-edge geometry: fcut, Y (1, sqrt3*unit) [fp32], edge_feats [bf16]
// ---------------------------------------------------------------------------
__global__ __launch_bounds__(256) void k_geom(
    const float* __restrict__ coords, const int* __restrict__ eidx, int E,
    float* __restrict__ fcut, float* __restrict__ Yb, bf16* __restrict__ ef) {
  int e = blockIdx.x * 256 + threadIdx.x;
  if (e >= E) return;
  int s = eidx[e], c = eidx[E + e];
  float dx = coords[c*3+0] - coords[s*3+0];
  float dy = coords[c*3+1] - coords[s*3+1];
  float dz = coords[c*3+2] - coords[s*3+2];
  float r = sqrtf(dx*dx + dy*dy + dz*dz + 1e-12f);
  float u = r * 0.2f;
  float u3 = u*u*u;
  float u6 = u3*u3, u7 = u6*u, u8 = u7*u;
  float fc = 1.f - 28.f*u6 + 48.f*u7 - 21.f*u8;
  fc = (u < 1.f) ? fc : 0.f;
  float inv_r = 1.f / r;
  fcut[e] = fc;
  Yb[e*4+0] = 1.f;
  Yb[e*4+1] = SQRT3_F * dx * inv_r;
  Yb[e*4+2] = SQRT3_F * dy * inv_r;
  Yb[e*4+3] = SQRT3_F * dz * inv_r;
  float pref = BESSEL_PREF * inv_r * fc;
  #pragma unroll
  for (int n = 1; n <= 8; ++n)
    ef[e*8 + n - 1] = f2b(pref * sinf((float)n * PI_F * u));
}

// ---------------------------------------------------------------------------
// Tiled fp32-compute GEMM over edges: 64 edges x NOUT per block, 256 threads.
// ---------------------------------------------------------------------------
template<int K, int KC, int NOUT, int AMODE, int EPI>
__global__ __launch_bounds__(256) void gemm_k(
    const bf16* __restrict__ A, const bf16* __restrict__ A2,
    const float* __restrict__ W, bf16* __restrict__ outb,
    const int* __restrict__ eidx, const float* __restrict__ nattr,
    const float* __restrict__ fcut, const float* __restrict__ Yb,
    float* __restrict__ env, float scale, int E) {
  constexpr int BM = 64;
  constexpr int BMP = BM + 1;
  constexpr int TN = NOUT / 16;
  __shared__ __align__(16) float As[KC * BMP];   // [k][e]
  __shared__ __align__(16) float Bs[KC * NOUT];  // [k][j]

  int tid = threadIdx.x;
  int tx = tid & 15, ty = tid >> 4;
  long e0 = (long)blockIdx.x * BM;
  float acc[4][TN];
  #pragma unroll
  for (int mm = 0; mm < 4; ++mm)
    #pragma unroll
    for (int nn = 0; nn < TN; ++nn) acc[mm][nn] = 0.f;

  for (int k0 = 0; k0 < K; k0 += KC) {
    for (int i = tid; i < BM * KC; i += 256) {
      int e = i / KC, k = i % KC;
      long eg = e0 + e;
      int kk = k0 + k;
      float v = 0.f;
      if (eg < E) {
        if constexpr (AMODE == AMODE_PLAIN) {
          v = b2f(A[eg * K + kk]);
        } else if constexpr (AMODE == AMODE_LATIN) {
          if (kk < 16)       { int c = eidx[E + eg]; v = nattr[(long)c*16 + kk]; }
          else if (kk < 32)  { int s = eidx[eg];     v = nattr[(long)s*16 + kk - 16]; }
          else               { v = b2f(A2[eg*8 + kk - 32]); }
        } else {
          v = (kk < 128) ? b2f(A[eg*128 + kk]) : b2f(A2[eg*64 + (kk - 128)]);
        }
      }
      As[k * BMP + e] = v;
    }
    for (int i = tid; i < KC * NOUT; i += 256) {
      int k = i / NOUT, j = i % NOUT;
      Bs[i] = W[(long)(k0 + k) * NOUT + j];
    }
    __syncthreads();
    #pragma unroll
    for (int k = 0; k < KC; ++k) {
      float a[4];
      #pragma unroll
      for (int mm = 0; mm < 4; ++mm) a[mm] = As[k * BMP + ty*4 + mm];
      float b[TN];
      #pragma unroll
      for (int nn = 0; nn < TN; nn += 4) {
        float4 t = *reinterpret_cast<const float4*>(&Bs[k * NOUT + tx*TN + nn]);
        b[nn] = t.x; b[nn+1] = t.y; b[nn+2] = t.z; b[nn+3] = t.w;
      }
      #pragma unroll
      for (int mm = 0; mm < 4; ++mm)
        #pragma unroll
        for (int nn = 0; nn < TN; ++nn)
          acc[mm][nn] = fmaf(a[mm], b[nn], acc[mm][nn]);
    }
    __syncthreads();
  }

  #pragma unroll
  for (int mm = 0; mm < 4; ++mm) {
    long eg = e0 + ty*4 + mm;
    if (eg >= E) continue;
    if constexpr (EPI == EPI_SILU) {
      #pragma unroll
      for (int nn = 0; nn < TN; ++nn)
        outb[eg * NOUT + tx*TN + nn] = f2b(silu_f(acc[mm][nn] * scale));
    } else if constexpr (EPI == EPI_ENVSPLIT) {
      if (tx < 8) {
        #pragma unroll
        for (int nn = 0; nn < TN; ++nn)
          outb[eg * 64 + tx*TN + nn] = f2b(acc[mm][nn] * scale);
      } else {
        int c = eidx[E + eg];
        float y1 = Yb[eg*4+1], y2 = Yb[eg*4+2], y3 = Yb[eg*4+3];
        float* base = env + (long)c * 128;
        #pragma unroll
        for (int nn = 0; nn < TN; nn += 2) {
          int jj = tx*TN + nn - 64;
          int mi = jj >> 1;
          float w0 = acc[mm][nn]   * scale;
          float w1 = acc[mm][nn+1] * scale;
          atomAddF(base + mi*4 + 0, w0);
          atomAddF(base + mi*4 + 1, w1 * y1);
          atomAddF(base + mi*4 + 2, w1 * y2);
          atomAddF(base + mi*4 + 3, w1 * y3);
        }
      }
    } else if constexpr (EPI == EPI_ENV1) {
      int c = eidx[E + eg];
      float y1 = Yb[eg*4+1], y2 = Yb[eg*4+2], y3 = Yb[eg*4+3];
      float* base = env + (long)c * 128;
      #pragma unroll
      for (int nn = 0; nn < TN; nn += 2) {
        int jj = tx*TN + nn;
        int mi = jj >> 1;
        float w0 = acc[mm][nn]   * scale;
        float w1 = acc[mm][nn+1] * scale;
        atomAddF(base + mi*4 + 0, w0);
        atomAddF(base + mi*4 + 1, w1 * y1);
        atomAddF(base + mi*4 + 2, w1 * y2);
        atomAddF(base + mi*4 + 3, w1 * y3);
      }
    }
  }
}

// ---------------------------------------------------------------------------
// Fused two-layer MLP: A(K) -> silu(@W0) hidden 128 in LDS -> @W1 -> epilogue.
// ---------------------------------------------------------------------------
template<int K, int KC, int AMODE, int EPI>
__global__ __launch_bounds__(256) void fused2_k(
    const bf16* __restrict__ A, const bf16* __restrict__ A2,
    const float* __restrict__ W0, const float* __restrict__ W1,
    bf16* __restrict__ outb, float* __restrict__ outf,
    const int* __restrict__ eidx, const float* __restrict__ fcut,
    const bf16* __restrict__ lat_old,
    float scale0, float scale1, int E) {
  constexpr int BM = 64;
  constexpr int BMP = BM + 1;
  __shared__ __align__(16) float As[KC * BMP];
  __shared__ __align__(16) float Bs[KC * 128];
  __shared__ __align__(16) float Hs[128 * BMP];

  int tid = threadIdx.x;
  int tx = tid & 15, ty = tid >> 4;
  long e0 = (long)blockIdx.x * BM;
  float acc[4][8];
  #pragma unroll
  for (int mm = 0; mm < 4; ++mm)
    #pragma unroll
    for (int nn = 0; nn < 8; ++nn) acc[mm][nn] = 0.f;

  for (int k0 = 0; k0 < K; k0 += KC) {
    for (int i = tid; i < BM * KC; i += 256) {
      int e = i / KC, k = i % KC;
      long eg = e0 + e;
      int kk = k0 + k;
      float v = 0.f;
      if (eg < E) {
        if constexpr (AMODE == AMODE_PLAIN) {
          v = b2f(A[eg * K + kk]);
        } else {
          v = (kk < 128) ? b2f(A[eg*128 + kk]) : b2f(A2[eg*64 + (kk - 128)]);
        }
      }
      As[k * BMP + e] = v;
    }
    for (int i = tid; i < KC * 128; i += 256) {
      int k = i / 128, j = i % 128;
      Bs[i] = W0[(long)(k0 + k) * 128 + j];
    }
    __syncthreads();
    #pragma unroll
    for (int k = 0; k < KC; ++k) {
      float a[4];
      #pragma unroll
      for (int mm = 0; mm < 4; ++mm) a[mm] = As[k * BMP + ty*4 + mm];
      float b[8];
      #pragma unroll
      for (int nn = 0; nn < 8; nn += 4) {
        float4 t = *reinterpret_cast<const float4*>(&Bs[k * 128 + tx*8 + nn]);
        b[nn] = t.x; b[nn+1] = t.y; b[nn+2] = t.z; b[nn+3] = t.w;
      }
      #pragma unroll
      for (int mm = 0; mm < 4; ++mm)
        #pragma unroll
        for (int nn = 0; nn < 8; ++nn)
          acc[mm][nn] = fmaf(a[mm], b[nn], acc[mm][nn]);
    }
    __syncthreads();
  }
  #pragma unroll
  for (int mm = 0; mm < 4; ++mm)
    #pragma unroll
    for (int nn = 0; nn < 8; ++nn)
      Hs[(tx*8 + nn) * BMP + (ty*4 + mm)] = silu_f(acc[mm][nn] * scale0);

  #pragma unroll
  for (int mm = 0; mm < 4; ++mm)
    #pragma unroll
    for (int nn = 0; nn < 8; ++nn) acc[mm][nn] = 0.f;

  for (int k0 = 0; k0 < 128; k0 += KC) {
    __syncthreads();
    for (int i = tid; i < KC * 128; i += 256) {
      int k = i / 128, j = i % 128;
      Bs[i] = W1[(long)(k0 + k) * 128 + j];
    }
    __syncthreads();
    #pragma unroll
    for (int k = 0; k < KC; ++k) {
      float a[4];
      #pragma unroll
      for (int mm = 0; mm < 4; ++mm) a[mm] = Hs[(k0 + k) * BMP + ty*4 + mm];
      float b[8];
      #pragma unroll
      for (int nn = 0; nn < 8; nn += 4) {
        float4 t = *reinterpret_cast<const float4*>(&Bs[k * 128 + tx*8 + nn]);
        b[nn] = t.x; b[nn+1] = t.y; b[nn+2] = t.z; b[nn+3] = t.w;
      }
      #pragma unroll
      for (int mm = 0; mm < 4; ++mm)
        #pragma unroll
        for (int nn = 0; nn < 8; ++nn)
          acc[mm][nn] = fmaf(a[mm], b[nn], acc[mm][nn]);
    }
  }

  #pragma unroll
  for (int mm = 0; mm < 4; ++mm) {
    long eg = e0 + ty*4 + mm;
    if (eg >= E) continue;
    float fc = fcut[eg];
    if constexpr (EPI == EPI_FCUT) {
      #pragma unroll
      for (int nn = 0; nn < 8; ++nn)
        outb[eg * 128 + tx*8 + nn] = f2b(acc[mm][nn] * scale1 * fc);
    } else if constexpr (EPI == EPI_RESID) {
      #pragma unroll
      for (int nn = 0; nn < 8; ++nn) {
        long idx = eg * 128 + tx*8 + nn;
        float v = acc[mm][nn] * scale1 * fc;
        outb[idx] = f2b(C_OLD * b2f(outb[idx]) + C_NEW * v);
      }
    } else { // EPI_FINAL: node segment-sum into fp32 nacc (workspace)
      int c = eidx[E + eg];
      #pragma unroll
      for (int nn = 0; nn < 8; ++nn) {
        int j = tx*8 + nn;
        float v = acc[mm][nn] * scale1 * fc;
        float lf = C_OLD * b2f(lat_old[eg*128 + j]) + C_NEW * v;
        atomAddF(outf + (long)c*128 + j, lf * INV_SQRT_N);
      }
    }
  }
}

// ---------------------------------------------------------------------------
__global__ __launch_bounds__(256) void k_prod(
    const bf16* __restrict__ wedge, const float* __restrict__ env,
    const float* __restrict__ Yb, const int* __restrict__ eidx, int E,
    bf16* __restrict__ scal) {
  long t = (long)blockIdx.x * 256 + threadIdx.x;
  if (t >= (long)E * 32) return;
  long e = t >> 5;
  int m = (int)(t & 31);
  int c = eidx[E + e];
  float w0 = b2f(wedge[e*64 + 2*m]), w1 = b2f(wedge[e*64 + 2*m + 1]);
  const float* ep = env + (long)c*128 + m*4;
  float es  = ep[0] * INV_SQRT_N;
  float evx = ep[1] * INV_SQRT_N, evy = ep[2] * INV_SQRT_N, evz = ep[3] * INV_SQRT_N;
  float y1 = Yb[e*4+1], y2 = Yb[e*4+2], y3 = Yb[e*4+3];
  float fvx = w1*y1, fvy = w1*y2, fvz = w1*y3;
  scal[e*64 + m]      = f2b(w0 * es);
  scal[e*64 + 32 + m] = f2b((fvx*evx + fvy*evy + fvz*evz) * INV_SQRT3);
}

// ---------------------------------------------------------------------------
#define MIX_TE 8
__global__ __launch_bounds__(256) void k_mix(
    const bf16* __restrict__ wedge, const float* __restrict__ env,
    const float* __restrict__ env1, const float* __restrict__ Yb,
    const int* __restrict__ eidx, int E,
    const float* __restrict__ Ws0, const float* __restrict__ Wv0,
    bf16* __restrict__ scal) {
  __shared__ float P[MIX_TE * 32 * 13];
  __shared__ float E1s[MIX_TE * 32 * 5];
  __shared__ float WS[64 * 32];
  __shared__ float WV[96 * 32];
  int tid = threadIdx.x;
  for (int i = tid; i < 64*32; i += 256) WS[i] = Ws0[i];
  for (int i = tid; i < 96*32; i += 256) WV[i] = Wv0[i];
  int el = tid >> 5, m = tid & 31;
  long e = (long)blockIdx.x * MIX_TE + el;
  bool valid = (e < E);
  if (valid) {
    int c = eidx[E + e];
    float w0 = b2f(wedge[e*64 + 2*m]), w1 = b2f(wedge[e*64 + 2*m + 1]);
    const float* ep = env + (long)c*128 + m*4;
    float es  = ep[0] * INV_SQRT_N;
    float evx = ep[1] * INV_SQRT_N, evy = ep[2] * INV_SQRT_N, evz = ep[3] * INV_SQRT_N;
    float y1 = Yb[e*4+1], y2 = Yb[e*4+2], y3 = Yb[e*4+3];
    float fvx = w1*y1, fvy = w1*y2, fvz = w1*y3;
    float* p = &P[(el*32 + m) * 13];
    p[0]  = w0 * es;
    p[1]  = (fvx*evx + fvy*evy + fvz*evz) * INV_SQRT3;
    p[2]  = w0 * evx; p[3] = w0 * evy; p[4] = w0 * evz;
    p[5]  = fvx * es; p[6] = fvy * es; p[7] = fvz * es;
    p[8]  = (fvy*evz - fvz*evy) * INV_SQRT2;
    p[9]  = (fvz*evx - fvx*evz) * INV_SQRT2;
    p[10] = (fvx*evy - fvy*evx) * INV_SQRT2;
    const float* e1p = env1 + (long)c*128 + m*4;
    float* qd = &E1s[(el*32 + m) * 5];
    qd[0] = e1p[0]*INV_SQRT_N; qd[1] = e1p[1]*INV_SQRT_N;
    qd[2] = e1p[2]*INV_SQRT_N; qd[3] = e1p[3]*INV_SQRT_N;
  }
  __syncthreads();
  if (!valid) return;
  int o = m;
  float s = 0.f, v0 = 0.f, v1 = 0.f, v2 = 0.f;
  for (int mm = 0; mm < 32; ++mm) {
    const float* pp = &P[(el*32 + mm) * 13];
    float ws0 = WS[mm*32 + o], ws1 = WS[(32+mm)*32 + o];
    s = fmaf(pp[0], ws0, s); s = fmaf(pp[1], ws1, s);
    float wa = WV[mm*32 + o], wb = WV[(32+mm)*32 + o], wc = WV[(64+mm)*32 + o];
    v0 = fmaf(pp[2], wa, v0); v0 = fmaf(pp[5], wb, v0); v0 = fmaf(pp[8],  wc, v0);
    v1 = fmaf(pp[3], wa, v1); v1 = fmaf(pp[6], wb, v1); v1 = fmaf(pp[9],  wc, v1);
    v2 = fmaf(pp[4], wa, v2); v2 = fmaf(pp[7], wb, v2); v2 = fmaf(pp[10], wc, v2);
  }
  s  *= 0.125f;
  v0 *= 0.10206207261596577f;
  v1 *= 0.10206207261596577f;
  v2 *= 0.10206207261596577f;
  const float* qv = &E1s[(el*32 + o) * 5];
  float q0 = s * qv[0];
  float q1 = (v0*qv[1] + v1*qv[2] + v2*qv[3]) * INV_SQRT3;
  scal[e*64 + o]      = f2b(q0);
  scal[e*64 + 32 + o] = f2b(q1);
}

// ---------------------------------------------------------------------------
__global__ __launch_bounds__(256) void k_cvt(
    const float* __restrict__ acc, float* __restrict__ out, int n) {
  int i = blockIdx.x * 256 + threadIdx.x;
  if (i < n) out[i] = acc[i];
}

// ---------------------------------------------------------------------------
extern "C" void kernel_launch(void* const* d_in, const int* in_sizes, int n_in,
                              void* d_out, int out_size, void* d_ws, size_t ws_size,
                              hipStream_t stream) {
  const float* coords = (const float*)d_in[0];
  const float* nattr  = (const float*)d_in[1];
  const int*   eidx   = (const int*)d_in[2];
  const float* W2b0   = (const float*)d_in[3];
  const float* W2b1   = (const float*)d_in[4];
  const float* W2b2   = (const float*)d_in[5];
  const float* Wenv0  = (const float*)d_in[6];
  const float* Wlat0  = (const float*)d_in[7];
  const float* Wlat1  = (const float*)d_in[8];
  const float* Ws0    = (const float*)d_in[9];
  const float* Wv0    = (const float*)d_in[10];
  const float* Wenv1  = (const float*)d_in[11];
  const float* Wfin0  = (const float*)d_in[12];
  const float* Wfin1  = (const float*)d_in[13];
  float* out = (float*)d_out;
  int E = in_sizes[2] / 2;     // 320000
  int N = in_sizes[0] / 3;     // 10000

  // workspace carve: fp32 regions then bf16 regions.  ~186 MB total.
  float* fcut = (float*)d_ws;                     // E
  float* Yb   = fcut + (size_t)E;                 // 4E
  float* env  = Yb + (size_t)E*4;                 // 128N
  float* env1 = env + (size_t)N*128;              // 128N
  float* nacc = env1 + (size_t)N*128;             // 128N
  bf16*  b64  = (bf16*)(nacc + (size_t)N*128);    // 64E  (h64, then w_edge)
  bf16*  lat  = b64 + (size_t)E*64;               // 128E
  bf16*  scal = lat + (size_t)E*128;              // 64E  (ef first 8E, then scal0/1)
  bf16*  ef   = scal;

  hipMemsetAsync(env,  0, (size_t)N * 128 * sizeof(float), stream);
  hipMemsetAsync(env1, 0, (size_t)N * 128 * sizeof(float), stream);
  hipMemsetAsync(nacc, 0, (size_t)N * 128 * sizeof(float), stream);

  dim3 blk(256);
  const float s40  = 0.15811388300841897f;  // 1/sqrt(40)
  const float s64  = 0.125f;
  const float s128 = 0.08838834764831845f;
  const float s192 = 0.07216878364870323f;
  int gB = (E + 63) / 64;

  k_geom<<<dim3((E + 255) / 256), blk, 0, stream>>>(coords, eidx, E, fcut, Yb, ef);

  // two-body MLP: 40 -> 64 (silu) -> fused [64 -> 128 silu -> 128] * fcut -> lat
  gemm_k<40,40,64,AMODE_LATIN,EPI_SILU><<<gB, blk, 0, stream>>>(
      nullptr, ef, W2b0, b64, eidx, nattr, fcut, Yb, nullptr, s40, E);
  fused2_k<64,32,AMODE_PLAIN,EPI_FCUT><<<gB, blk, 0, stream>>>(
      b64, nullptr, W2b1, W2b2, lat, nullptr, eidx, fcut, nullptr, s64, s128, E);

  // Wenv0: w_edge -> b64, w_env -> env atomics
  gemm_k<128,32,128,AMODE_PLAIN,EPI_ENVSPLIT><<<gB, blk, 0, stream>>>(
      lat, nullptr, Wenv0, b64, eidx, nattr, fcut, Yb, env, s128, E);

  // products -> scal0
  k_prod<<<dim3((int)(((long)E*32 + 255) / 256)), blk, 0, stream>>>(
      b64, env, Yb, eidx, E, scal);

  // latent MLP (fused 192 -> 128 silu -> 128) * fcut, residual into lat
  fused2_k<192,32,AMODE_CONCAT,EPI_RESID><<<gB, blk, 0, stream>>>(
      lat, scal, Wlat0, Wlat1, lat, nullptr, eidx, fcut, nullptr, s192, s128, E);

  // Wenv1 -> env1 atomics
  gemm_k<128,32,64,AMODE_PLAIN,EPI_ENV1><<<gB, blk, 0, stream>>>(
      lat, nullptr, Wenv1, nullptr, eidx, nattr, fcut, Yb, env1, s128, E);

  // mix -> scal1
  k_mix<<<dim3((E + MIX_TE - 1) / MIX_TE), blk, 0, stream>>>(
      b64, env, env1, Yb, eidx, E, Ws0, Wv0, scal);

  // final MLP (fused) + residual + node segment-sum into nacc
  fused2_k<192,32,AMODE_CONCAT,EPI_FINAL><<<gB, blk, 0, stream>>>(
      lat, scal, Wfin0, Wfin1, nullptr, nacc, eidx, fcut, lat, s192, s128, E);

  // nacc -> d_out
  k_cvt<<<dim3((N*128 + 255) / 256), blk, 0, stream>>>(nacc, out, N*128);
}

// Round 6
// 3536.562 us; speedup vs baseline: 2.1163x; 2.0851x over previous
//
#include <hip/hip_runtime.h>
#include <hip/hip_bf16.h>
#include <math.h>

typedef __hip_bfloat16 bf16;

#define AMODE_PLAIN  0
#define AMODE_LATIN  1
#define AMODE_CONCAT 2
#define EPI_SILU     0
#define EPI_SPLIT    1
#define EPI_STORE    2
#define EPI_FCUT     3
#define EPI_RESID    4

#define INV_SQRT_N 0.17677669529663687f   /* 1/sqrt(32) */
#define INV_SQRT3  0.5773502691896258f
#define INV_SQRT2  0.7071067811865476f
#define C_OLD      0.8944271909999159f    /* 1/sqrt(1.25) */
#define C_NEW      0.4472135954999579f
#define PI_F       3.14159265358979323846f
#define SQRT3_F    1.7320508075688772f
#define BESSEL_PREF 0.6324555320336759f   /* sqrt(2/5) */

__device__ __forceinline__ float b2f(bf16 x) { return __bfloat162float(x); }
__device__ __forceinline__ bf16  f2b(float x) { return __float2bfloat16(x); }
__device__ __forceinline__ float silu_f(float v) { return v / (1.f + __expf(-v)); }

// ---------------------------------------------------------------------------
// per-edge geometry
// ---------------------------------------------------------------------------
__global__ __launch_bounds__(256) void k_geom(
    const float* __restrict__ coords, const int* __restrict__ eidx, int E,
    float* __restrict__ fcut, float* __restrict__ Yb, bf16* __restrict__ ef) {
  int e = blockIdx.x * 256 + threadIdx.x;
  if (e >= E) return;
  int s = eidx[e], c = eidx[E + e];
  float dx = coords[c*3+0] - coords[s*3+0];
  float dy = coords[c*3+1] - coords[s*3+1];
  float dz = coords[c*3+2] - coords[s*3+2];
  float r = sqrtf(dx*dx + dy*dy + dz*dz + 1e-12f);
  float u = r * 0.2f;
  float u3 = u*u*u;
  float u6 = u3*u3, u7 = u6*u, u8 = u7*u;
  float fc = 1.f - 28.f*u6 + 48.f*u7 - 21.f*u8;
  fc = (u < 1.f) ? fc : 0.f;
  float inv_r = 1.f / r;
  fcut[e] = fc;
  Yb[e*4+0] = 1.f;
  Yb[e*4+1] = SQRT3_F * dx * inv_r;
  Yb[e*4+2] = SQRT3_F * dy * inv_r;
  Yb[e*4+3] = SQRT3_F * dz * inv_r;
  float pref = BESSEL_PREF * inv_r * fc;
  #pragma unroll
  for (int n = 1; n <= 8; ++n)
    ef[e*8 + n - 1] = f2b(pref * sinf((float)n * PI_F * u));
}

// ---------------------------------------------------------------------------
// CSR build: deg -> rowptr/cursor (1-block scan) -> eord
// ---------------------------------------------------------------------------
__global__ __launch_bounds__(256) void k_deg(
    const int* __restrict__ eidx, int E, int* __restrict__ deg) {
  int e = blockIdx.x * 256 + threadIdx.x;
  if (e < E) atomicAdd(&deg[eidx[E + e]], 1);
}

__global__ __launch_bounds__(1024) void k_scan(
    const int* __restrict__ deg, int N,
    int* __restrict__ rowptr, int* __restrict__ cursor) {
  __shared__ int part[1024];
  int t = threadIdx.x;
  int C = (N + 1023) / 1024;
  int base = t * C;
  int s = 0;
  for (int i = 0; i < C; ++i) { int idx = base + i; if (idx < N) s += deg[idx]; }
  part[t] = s;
  __syncthreads();
  for (int off = 1; off < 1024; off <<= 1) {
    int v = (t >= off) ? part[t - off] : 0;
    __syncthreads();
    part[t] += v;
    __syncthreads();
  }
  int excl = (t == 0) ? 0 : part[t - 1];
  for (int i = 0; i < C; ++i) {
    int idx = base + i;
    if (idx < N) { rowptr[idx] = excl; cursor[idx] = excl; excl += deg[idx]; }
  }
  if (t == 0) rowptr[N] = part[1023];
}

__global__ __launch_bounds__(256) void k_fill(
    const int* __restrict__ eidx, int E, int* __restrict__ cursor,
    int* __restrict__ eord) {
  int e = blockIdx.x * 256 + threadIdx.x;
  if (e >= E) return;
  int c = eidx[E + e];
  int slot = atomicAdd(&cursor[c], 1);
  eord[slot] = e;
}

// ---------------------------------------------------------------------------
// env gather: env[n][m][0:4] = sum over edges of (w0, w1*y1, w1*y2, w1*y3)
// thread = (node, m); wave = 2 nodes x 32 m; w reads 128B-coalesced.
// ---------------------------------------------------------------------------
__global__ __launch_bounds__(256) void k_envg(
    const bf16* __restrict__ wenv, const float* __restrict__ Yb,
    const int* __restrict__ rowptr, const int* __restrict__ eord,
    int N, float* __restrict__ env) {
  int t = blockIdx.x * 256 + threadIdx.x;
  if (t >= N * 32) return;
  int n = t >> 5, m = t & 31;
  int j0 = rowptr[n], j1 = rowptr[n + 1];
  float a0 = 0.f, a1 = 0.f, a2 = 0.f, a3 = 0.f;
  for (int j = j0; j < j1; ++j) {
    int e = eord[j];
    float w0 = b2f(wenv[(long)e*64 + 2*m]);
    float w1 = b2f(wenv[(long)e*64 + 2*m + 1]);
    float4 y = *reinterpret_cast<const float4*>(&Yb[(long)e*4]);
    a0 += w0;
    a1 += w1 * y.y;
    a2 += w1 * y.z;
    a3 += w1 * y.w;
  }
  *reinterpret_cast<float4*>(&env[(long)n*128 + m*4]) = make_float4(a0, a1, a2, a3);
}

// ---------------------------------------------------------------------------
// node gather: out[n][j] = INV_SQRT_N * sum over edges of lat[e][j]
// ---------------------------------------------------------------------------
__global__ __launch_bounds__(256) void k_nodeg(
    const bf16* __restrict__ lat, const int* __restrict__ rowptr,
    const int* __restrict__ eord, int N, float* __restrict__ out) {
  int t = blockIdx.x * 256 + threadIdx.x;
  if (t >= N * 128) return;
  int n = t >> 7, j = t & 127;
  int j0 = rowptr[n], j1 = rowptr[n + 1];
  float s = 0.f;
  for (int q = j0; q < j1; ++q) {
    int e = eord[q];
    s += b2f(lat[(long)e*128 + j]);
  }
  out[t] = s * INV_SQRT_N;
}

// ---------------------------------------------------------------------------
// Tiled fp32-compute GEMM over edges: 64 edges x NOUT per block, 256 threads.
// ---------------------------------------------------------------------------
template<int K, int KC, int NOUT, int AMODE, int EPI>
__global__ __launch_bounds__(256) void gemm_k(
    const bf16* __restrict__ A, const bf16* __restrict__ A2,
    const float* __restrict__ W, bf16* __restrict__ outb,
    bf16* __restrict__ outb2, const int* __restrict__ eidx,
    const float* __restrict__ nattr, float scale, int E) {
  constexpr int BM = 64;
  constexpr int BMP = BM + 1;
  constexpr int TN = NOUT / 16;
  __shared__ __align__(16) float As[KC * BMP];   // [k][e]
  __shared__ __align__(16) float Bs[KC * NOUT];  // [k][j]

  int tid = threadIdx.x;
  int tx = tid & 15, ty = tid >> 4;
  long e0 = (long)blockIdx.x * BM;
  float acc[4][TN];
  #pragma unroll
  for (int mm = 0; mm < 4; ++mm)
    #pragma unroll
    for (int nn = 0; nn < TN; ++nn) acc[mm][nn] = 0.f;

  for (int k0 = 0; k0 < K; k0 += KC) {
    for (int i = tid; i < BM * KC; i += 256) {
      int e = i / KC, k = i % KC;
      long eg = e0 + e;
      int kk = k0 + k;
      float v = 0.f;
      if (eg < E) {
        if constexpr (AMODE == AMODE_PLAIN) {
          v = b2f(A[eg * K + kk]);
        } else if constexpr (AMODE == AMODE_LATIN) {
          if (kk < 16)       { int c = eidx[E + eg]; v = nattr[(long)c*16 + kk]; }
          else if (kk < 32)  { int s = eidx[eg];     v = nattr[(long)s*16 + kk - 16]; }
          else               { v = b2f(A2[eg*8 + kk - 32]); }
        } else {
          v = (kk < 128) ? b2f(A[eg*128 + kk]) : b2f(A2[eg*64 + (kk - 128)]);
        }
      }
      As[k * BMP + e] = v;
    }
    for (int i = tid; i < KC * NOUT; i += 256) {
      int k = i / NOUT, j = i % NOUT;
      Bs[i] = W[(long)(k0 + k) * NOUT + j];
    }
    __syncthreads();
    #pragma unroll
    for (int k = 0; k < KC; ++k) {
      float a[4];
      #pragma unroll
      for (int mm = 0; mm < 4; ++mm) a[mm] = As[k * BMP + ty*4 + mm];
      float b[TN];
      #pragma unroll
      for (int nn = 0; nn < TN; nn += 4) {
        float4 t = *reinterpret_cast<const float4*>(&Bs[k * NOUT + tx*TN + nn]);
        b[nn] = t.x; b[nn+1] = t.y; b[nn+2] = t.z; b[nn+3] = t.w;
      }
      #pragma unroll
      for (int mm = 0; mm < 4; ++mm)
        #pragma unroll
        for (int nn = 0; nn < TN; ++nn)
          acc[mm][nn] = fmaf(a[mm], b[nn], acc[mm][nn]);
    }
    __syncthreads();
  }

  #pragma unroll
  for (int mm = 0; mm < 4; ++mm) {
    long eg = e0 + ty*4 + mm;
    if (eg >= E) continue;
    if constexpr (EPI == EPI_SILU) {
      #pragma unroll
      for (int nn = 0; nn < TN; ++nn)
        outb[eg * NOUT + tx*TN + nn] = f2b(silu_f(acc[mm][nn] * scale));
    } else if constexpr (EPI == EPI_SPLIT) {
      // cols 0..63 -> w_edge (outb), cols 64..127 -> w_env (outb2)
      #pragma unroll
      for (int nn = 0; nn < TN; ++nn) {
        int j = tx*TN + nn;
        bf16 v = f2b(acc[mm][nn] * scale);
        if (j < 64) outb[eg * 64 + j] = v;
        else        outb2[eg * 64 + (j - 64)] = v;
      }
    } else { // EPI_STORE
      #pragma unroll
      for (int nn = 0; nn < TN; ++nn)
        outb[eg * NOUT + tx*TN + nn] = f2b(acc[mm][nn] * scale);
    }
  }
}

// ---------------------------------------------------------------------------
// Fused two-layer MLP: A(K) -> silu(@W0) hidden 128 in LDS -> @W1 -> epilogue.
// ---------------------------------------------------------------------------
template<int K, int KC, int AMODE, int EPI>
__global__ __launch_bounds__(256) void fused2_k(
    const bf16* __restrict__ A, const bf16* __restrict__ A2,
    const float* __restrict__ W0, const float* __restrict__ W1,
    bf16* __restrict__ outb, const float* __restrict__ fcut,
    float scale0, float scale1, int E) {
  constexpr int BM = 64;
  constexpr int BMP = BM + 1;
  __shared__ __align__(16) float As[KC * BMP];
  __shared__ __align__(16) float Bs[KC * 128];
  __shared__ __align__(16) float Hs[128 * BMP];

  int tid = threadIdx.x;
  int tx = tid & 15, ty = tid >> 4;
  long e0 = (long)blockIdx.x * BM;
  float acc[4][8];
  #pragma unroll
  for (int mm = 0; mm < 4; ++mm)
    #pragma unroll
    for (int nn = 0; nn < 8; ++nn) acc[mm][nn] = 0.f;

  for (int k0 = 0; k0 < K; k0 += KC) {
    for (int i = tid; i < BM * KC; i += 256) {
      int e = i / KC, k = i % KC;
      long eg = e0 + e;
      int kk = k0 + k;
      float v = 0.f;
      if (eg < E) {
        if constexpr (AMODE == AMODE_PLAIN) {
          v = b2f(A[eg * K + kk]);
        } else {
          v = (kk < 128) ? b2f(A[eg*128 + kk]) : b2f(A2[eg*64 + (kk - 128)]);
        }
      }
      As[k * BMP + e] = v;
    }
    for (int i = tid; i < KC * 128; i += 256) {
      int k = i / 128, j = i % 128;
      Bs[i] = W0[(long)(k0 + k) * 128 + j];
    }
    __syncthreads();
    #pragma unroll
    for (int k = 0; k < KC; ++k) {
      float a[4];
      #pragma unroll
      for (int mm = 0; mm < 4; ++mm) a[mm] = As[k * BMP + ty*4 + mm];
      float b[8];
      #pragma unroll
      for (int nn = 0; nn < 8; nn += 4) {
        float4 t = *reinterpret_cast<const float4*>(&Bs[k * 128 + tx*8 + nn]);
        b[nn] = t.x; b[nn+1] = t.y; b[nn+2] = t.z; b[nn+3] = t.w;
      }
      #pragma unroll
      for (int mm = 0; mm < 4; ++mm)
        #pragma unroll
        for (int nn = 0; nn < 8; ++nn)
          acc[mm][nn] = fmaf(a[mm], b[nn], acc[mm][nn]);
    }
    __syncthreads();
  }
  #pragma unroll
  for (int mm = 0; mm < 4; ++mm)
    #pragma unroll
    for (int nn = 0; nn < 8; ++nn)
      Hs[(tx*8 + nn) * BMP + (ty*4 + mm)] = silu_f(acc[mm][nn] * scale0);

  #pragma unroll
  for (int mm = 0; mm < 4; ++mm)
    #pragma unroll
    for (int nn = 0; nn < 8; ++nn) acc[mm][nn] = 0.f;

  for (int k0 = 0; k0 < 128; k0 += KC) {
    __syncthreads();
    for (int i = tid; i < KC * 128; i += 256) {
      int k = i / 128, j = i % 128;
      Bs[i] = W1[(long)(k0 + k) * 128 + j];
    }
    __syncthreads();
    #pragma unroll
    for (int k = 0; k < KC; ++k) {
      float a[4];
      #pragma unroll
      for (int mm = 0; mm < 4; ++mm) a[mm] = Hs[(k0 + k) * BMP + ty*4 + mm];
      float b[8];
      #pragma unroll
      for (int nn = 0; nn < 8; nn += 4) {
        float4 t = *reinterpret_cast<const float4*>(&Bs[k * 128 + tx*8 + nn]);
        b[nn] = t.x; b[nn+1] = t.y; b[nn+2] = t.z; b[nn+3] = t.w;
      }
      #pragma unroll
      for (int mm = 0; mm < 4; ++mm)
        #pragma unroll
        for (int nn = 0; nn < 8; ++nn)
          acc[mm][nn] = fmaf(a[mm], b[nn], acc[mm][nn]);
    }
  }

  #pragma unroll
  for (int mm = 0; mm < 4; ++mm) {
    long eg = e0 + ty*4 + mm;
    if (eg >= E) continue;
    float fc = fcut[eg];
    if constexpr (EPI == EPI_FCUT) {
      #pragma unroll
      for (int nn = 0; nn < 8; ++nn)
        outb[eg * 128 + tx*8 + nn] = f2b(acc[mm][nn] * scale1 * fc);
    } else { // EPI_RESID (in-place safe: block-private rows)
      #pragma unroll
      for (int nn = 0; nn < 8; ++nn) {
        long idx = eg * 128 + tx*8 + nn;
        float v = acc[mm][nn] * scale1 * fc;
        outb[idx] = f2b(C_OLD * b2f(outb[idx]) + C_NEW * v);
      }
    }
  }
}

// ---------------------------------------------------------------------------
__global__ __launch_bounds__(256) void k_prod(
    const bf16* __restrict__ wedge, const float* __restrict__ env,
    const float* __restrict__ Yb, const int* __restrict__ eidx, int E,
    bf16* __restrict__ scal) {
  long t = (long)blockIdx.x * 256 + threadIdx.x;
  if (t >= (long)E * 32) return;
  long e = t >> 5;
  int m = (int)(t & 31);
  int c = eidx[E + e];
  float w0 = b2f(wedge[e*64 + 2*m]), w1 = b2f(wedge[e*64 + 2*m + 1]);
  const float* ep = env + (long)c*128 + m*4;
  float es  = ep[0] * INV_SQRT_N;
  float evx = ep[1] * INV_SQRT_N, evy = ep[2] * INV_SQRT_N, evz = ep[3] * INV_SQRT_N;
  float y1 = Yb[e*4+1], y2 = Yb[e*4+2], y3 = Yb[e*4+3];
  float fvx = w1*y1, fvy = w1*y2, fvz = w1*y3;
  scal[e*64 + m]      = f2b(w0 * es);
  scal[e*64 + 32 + m] = f2b((fvx*evx + fvy*evy + fvz*evz) * INV_SQRT3);
}

// ---------------------------------------------------------------------------
#define MIX_TE 8
__global__ __launch_bounds__(256) void k_mix(
    const bf16* __restrict__ wedge, const float* __restrict__ env,
    const float* __restrict__ env1, const float* __restrict__ Yb,
    const int* __restrict__ eidx, int E,
    const float* __restrict__ Ws0, const float* __restrict__ Wv0,
    bf16* __restrict__ scal) {
  __shared__ float P[MIX_TE * 32 * 13];
  __shared__ float E1s[MIX_TE * 32 * 5];
  __shared__ float WS[64 * 32];
  __shared__ float WV[96 * 32];
  int tid = threadIdx.x;
  for (int i = tid; i < 64*32; i += 256) WS[i] = Ws0[i];
  for (int i = tid; i < 96*32; i += 256) WV[i] = Wv0[i];
  int el = tid >> 5, m = tid & 31;
  long e = (long)blockIdx.x * MIX_TE + el;
  bool valid = (e < E);
  if (valid) {
    int c = eidx[E + e];
    float w0 = b2f(wedge[e*64 + 2*m]), w1 = b2f(wedge[e*64 + 2*m + 1]);
    const float* ep = env + (long)c*128 + m*4;
    float es  = ep[0] * INV_SQRT_N;
    float evx = ep[1] * INV_SQRT_N, evy = ep[2] * INV_SQRT_N, evz = ep[3] * INV_SQRT_N;
    float y1 = Yb[e*4+1], y2 = Yb[e*4+2], y3 = Yb[e*4+3];
    float fvx = w1*y1, fvy = w1*y2, fvz = w1*y3;
    float* p = &P[(el*32 + m) * 13];
    p[0]  = w0 * es;
    p[1]  = (fvx*evx + fvy*evy + fvz*evz) * INV_SQRT3;
    p[2]  = w0 * evx; p[3] = w0 * evy; p[4] = w0 * evz;
    p[5]  = fvx * es; p[6] = fvy * es; p[7] = fvz * es;
    p[8]  = (fvy*evz - fvz*evy) * INV_SQRT2;
    p[9]  = (fvz*evx - fvx*evz) * INV_SQRT2;
    p[10] = (fvx*evy - fvy*evx) * INV_SQRT2;
    const float* e1p = env1 + (long)c*128 + m*4;
    float* qd = &E1s[(el*32 + m) * 5];
    qd[0] = e1p[0]*INV_SQRT_N; qd[1] = e1p[1]*INV_SQRT_N;
    qd[2] = e1p[2]*INV_SQRT_N; qd[3] = e1p[3]*INV_SQRT_N;
  }
  __syncthreads();
  if (!valid) return;
  int o = m;
  float s = 0.f, v0 = 0.f, v1 = 0.f, v2 = 0.f;
  for (int mm = 0; mm < 32; ++mm) {
    const float* pp = &P[(el*32 + mm) * 13];
    float ws0 = WS[mm*32 + o], ws1 = WS[(32+mm)*32 + o];
    s = fmaf(pp[0], ws0, s); s = fmaf(pp[1], ws1, s);
    float wa = WV[mm*32 + o], wb = WV[(32+mm)*32 + o], wc = WV[(64+mm)*32 + o];
    v0 = fmaf(pp[2], wa, v0); v0 = fmaf(pp[5], wb, v0); v0 = fmaf(pp[8],  wc, v0);
    v1 = fmaf(pp[3], wa, v1); v1 = fmaf(pp[6], wb, v1); v1 = fmaf(pp[9],  wc, v1);
    v2 = fmaf(pp[4], wa, v2); v2 = fmaf(pp[7], wb, v2); v2 = fmaf(pp[10], wc, v2);
  }
  s  *= 0.125f;
  v0 *= 0.10206207261596577f;
  v1 *= 0.10206207261596577f;
  v2 *= 0.10206207261596577f;
  const float* qv = &E1s[(el*32 + o) * 5];
  float q0 = s * qv[0];
  float q1 = (v0*qv[1] + v1*qv[2] + v2*qv[3]) * INV_SQRT3;
  scal[e*64 + o]      = f2b(q0);
  scal[e*64 + 32 + o] = f2b(q1);
}

// ---------------------------------------------------------------------------
extern "C" void kernel_launch(void* const* d_in, const int* in_sizes, int n_in,
                              void* d_out, int out_size, void* d_ws, size_t ws_size,
                              hipStream_t stream) {
  const float* coords = (const float*)d_in[0];
  const float* nattr  = (const float*)d_in[1];
  const int*   eidx   = (const int*)d_in[2];
  const float* W2b0   = (const float*)d_in[3];
  const float* W2b1   = (const float*)d_in[4];
  const float* W2b2   = (const float*)d_in[5];
  const float* Wenv0  = (const float*)d_in[6];
  const float* Wlat0  = (const float*)d_in[7];
  const float* Wlat1  = (const float*)d_in[8];
  const float* Ws0    = (const float*)d_in[9];
  const float* Wv0    = (const float*)d_in[10];
  const float* Wenv1  = (const float*)d_in[11];
  const float* Wfin0  = (const float*)d_in[12];
  const float* Wfin1  = (const float*)d_in[13];
  float* out = (float*)d_out;
  int E = in_sizes[2] / 2;     // 320000
  int N = in_sizes[0] / 3;     // 10000

  // workspace carve (~182 MB): fp32, then int (CSR), then bf16.
  float* fcut   = (float*)d_ws;                    // E
  float* Yb     = fcut + (size_t)E;                // 4E
  float* env    = Yb + (size_t)E*4;                // 128N
  float* env1   = env + (size_t)N*128;             // 128N
  int*   deg    = (int*)(env1 + (size_t)N*128);    // N
  int*   rowptr = deg + N;                         // N+8 (padded)
  int*   cursor = rowptr + (N + 8);                // N
  int*   eord   = cursor + N;                      // E
  bf16*  b64    = (bf16*)(eord + E);               // 64E  (h64, then wedge)
  bf16*  lat    = b64 + (size_t)E*64;              // 128E
  bf16*  S      = lat + (size_t)E*128;             // 64E  (ef/wenv/scal0/wenv1/scal1)

  hipMemsetAsync(deg, 0, (size_t)N * sizeof(int), stream);

  dim3 blk(256);
  const float s40  = 0.15811388300841897f;  // 1/sqrt(40)
  const float s64  = 0.125f;
  const float s128 = 0.08838834764831845f;
  const float s192 = 0.07216878364870323f;
  int gB = (E + 63) / 64;
  int gE = (E + 255) / 256;

  // geometry + CSR build
  k_geom<<<gE, blk, 0, stream>>>(coords, eidx, E, fcut, Yb, S /*ef*/);
  k_deg<<<gE, blk, 0, stream>>>(eidx, E, deg);
  k_scan<<<1, 1024, 0, stream>>>(deg, N, rowptr, cursor);
  k_fill<<<gE, blk, 0, stream>>>(eidx, E, cursor, eord);

  // two-body MLP: 40 -> 64 (silu) -> fused [64 -> 128 silu -> 128] * fcut
  gemm_k<40,40,64,AMODE_LATIN,EPI_SILU><<<gB, blk, 0, stream>>>(
      nullptr, S /*ef*/, W2b0, b64, nullptr, eidx, nattr, s40, E);
  fused2_k<64,32,AMODE_PLAIN,EPI_FCUT><<<gB, blk, 0, stream>>>(
      b64, nullptr, W2b1, W2b2, lat, fcut, s64, s128, E);

  // Wenv0: w_edge -> b64, w_env -> S (plain stores, no atomics)
  gemm_k<128,32,128,AMODE_PLAIN,EPI_SPLIT><<<gB, blk, 0, stream>>>(
      lat, nullptr, Wenv0, b64, S /*wenv*/, eidx, nattr, s128, E);

  // env = CSR gather of w_env
  k_envg<<<dim3((N*32 + 255) / 256), blk, 0, stream>>>(
      S /*wenv*/, Yb, rowptr, eord, N, env);

  // products -> scal0 (overwrites S; wenv dead)
  k_prod<<<dim3((int)(((long)E*32 + 255) / 256)), blk, 0, stream>>>(
      b64, env, Yb, eidx, E, S /*scal0*/);

  // latent MLP (fused 192 -> 128 silu -> 128) * fcut, residual into lat
  fused2_k<192,32,AMODE_CONCAT,EPI_RESID><<<gB, blk, 0, stream>>>(
      lat, S /*scal0*/, Wlat0, Wlat1, lat, fcut, s192, s128, E);

  // Wenv1 -> wenv1 stores into S (scal0 dead)
  gemm_k<128,32,64,AMODE_PLAIN,EPI_STORE><<<gB, blk, 0, stream>>>(
      lat, nullptr, Wenv1, S /*wenv1*/, nullptr, eidx, nattr, s128, E);

  // env1 = CSR gather
  k_envg<<<dim3((N*32 + 255) / 256), blk, 0, stream>>>(
      S /*wenv1*/, Yb, rowptr, eord, N, env1);

  // mix -> scal1 into S (wenv1 dead)
  k_mix<<<dim3((E + MIX_TE - 1) / MIX_TE), blk, 0, stream>>>(
      b64, env, env1, Yb, eidx, E, Ws0, Wv0, S /*scal1*/);

  // final MLP (fused) + residual, lat updated in place
  fused2_k<192,32,AMODE_CONCAT,EPI_RESID><<<gB, blk, 0, stream>>>(
      lat, S /*scal1*/, Wfin0, Wfin1, lat, fcut, s192, s128, E);

  // node segment-sum by CSR gather -> d_out (fully written, no memset needed)
  k_nodeg<<<dim3((N*128 + 255) / 256), blk, 0, stream>>>(
      lat, rowptr, eord, N, out);
}

// Round 7
// 1192.491 us; speedup vs baseline: 6.2762x; 2.9657x over previous
//
#include <hip/hip_runtime.h>
#include <hip/hip_bf16.h>
#include <math.h>

typedef __hip_bfloat16 bf16;
typedef __attribute__((ext_vector_type(8))) short short8;
typedef __attribute__((ext_vector_type(4))) float floatx4;

#define AMODE_PLAIN  0
#define AMODE_LATIN  1
#define AMODE_CONCAT 2
#define EPI_SILU     0
#define EPI_SPLIT    1
#define EPI_STORE    2
#define EPI_FCUT     3
#define EPI_RESID    4

#define INV_SQRT_N 0.17677669529663687f   /* 1/sqrt(32) */
#define INV_SQRT3  0.5773502691896258f
#define INV_SQRT2  0.7071067811865476f
#define C_OLD      0.8944271909999159f    /* 1/sqrt(1.25) */
#define C_NEW      0.4472135954999579f
#define PI_F       3.14159265358979323846f
#define SQRT3_F    1.7320508075688772f
#define BESSEL_PREF 0.6324555320336759f   /* sqrt(2/5) */

__device__ __forceinline__ float b2f(bf16 x) { return __bfloat162float(x); }
__device__ __forceinline__ bf16  f2b(float x) { return __float2bfloat16(x); }
__device__ __forceinline__ unsigned short f2bu(float x) {
  bf16 h = f2b(x); unsigned short u; __builtin_memcpy(&u, &h, 2); return u;
}
__device__ __forceinline__ float silu_f(float v) { return v / (1.f + __expf(-v)); }
__device__ __forceinline__ floatx4 mfma16(short8 a, short8 b, floatx4 c) {
  return __builtin_amdgcn_mfma_f32_16x16x32_bf16(a, b, c, 0, 0, 0);
}

// ---------------------------------------------------------------------------
// per-edge geometry
// ---------------------------------------------------------------------------
__global__ __launch_bounds__(256) void k_geom(
    const float* __restrict__ coords, const int* __restrict__ eidx, int E,
    float* __restrict__ fcut, float* __restrict__ Yb, bf16* __restrict__ ef) {
  int e = blockIdx.x * 256 + threadIdx.x;
  if (e >= E) return;
  int s = eidx[e], c = eidx[E + e];
  float dx = coords[c*3+0] - coords[s*3+0];
  float dy = coords[c*3+1] - coords[s*3+1];
  float dz = coords[c*3+2] - coords[s*3+2];
  float r = sqrtf(dx*dx + dy*dy + dz*dz + 1e-12f);
  float u = r * 0.2f;
  float u3 = u*u*u;
  float u6 = u3*u3, u7 = u6*u, u8 = u7*u;
  float fc = 1.f - 28.f*u6 + 48.f*u7 - 21.f*u8;
  fc = (u < 1.f) ? fc : 0.f;
  float inv_r = 1.f / r;
  fcut[e] = fc;
  Yb[e*4+0] = 1.f;
  Yb[e*4+1] = SQRT3_F * dx * inv_r;
  Yb[e*4+2] = SQRT3_F * dy * inv_r;
  Yb[e*4+3] = SQRT3_F * dz * inv_r;
  float pref = BESSEL_PREF * inv_r * fc;
  #pragma unroll
  for (int n = 1; n <= 8; ++n)
    ef[e*8 + n - 1] = f2b(pref * sinf((float)n * PI_F * u));
}

// ---------------------------------------------------------------------------
// CSR build
// ---------------------------------------------------------------------------
__global__ __launch_bounds__(256) void k_deg(
    const int* __restrict__ eidx, int E, int* __restrict__ deg) {
  int e = blockIdx.x * 256 + threadIdx.x;
  if (e < E) atomicAdd(&deg[eidx[E + e]], 1);
}

__global__ __launch_bounds__(1024) void k_scan(
    const int* __restrict__ deg, int N,
    int* __restrict__ rowptr, int* __restrict__ cursor) {
  __shared__ int part[1024];
  int t = threadIdx.x;
  int C = (N + 1023) / 1024;
  int base = t * C;
  int s = 0;
  for (int i = 0; i < C; ++i) { int idx = base + i; if (idx < N) s += deg[idx]; }
  part[t] = s;
  __syncthreads();
  for (int off = 1; off < 1024; off <<= 1) {
    int v = (t >= off) ? part[t - off] : 0;
    __syncthreads();
    part[t] += v;
    __syncthreads();
  }
  int excl = (t == 0) ? 0 : part[t - 1];
  for (int i = 0; i < C; ++i) {
    int idx = base + i;
    if (idx < N) { rowptr[idx] = excl; cursor[idx] = excl; excl += deg[idx]; }
  }
  if (t == 0) rowptr[N] = part[1023];
}

__global__ __launch_bounds__(256) void k_fill(
    const int* __restrict__ eidx, int E, int* __restrict__ cursor,
    int* __restrict__ eord) {
  int e = blockIdx.x * 256 + threadIdx.x;
  if (e >= E) return;
  int c = eidx[E + e];
  int slot = atomicAdd(&cursor[c], 1);
  eord[slot] = e;
}

// ---------------------------------------------------------------------------
// weight prep: fp32 W[k][n] -> bf16 Wt[n][k]
// ---------------------------------------------------------------------------
__global__ __launch_bounds__(256) void k_wprep(
    const float* __restrict__ W, unsigned short* __restrict__ Wt, int K, int NOUT) {
  int t = blockIdx.x * 256 + threadIdx.x;
  if (t >= K * NOUT) return;
  int n = t / K, k = t % K;
  Wt[n * K + k] = f2bu(W[k * NOUT + n]);
}

// ---------------------------------------------------------------------------
// env gather (CSR)
// ---------------------------------------------------------------------------
__global__ __launch_bounds__(256) void k_envg(
    const bf16* __restrict__ wenv, const float* __restrict__ Yb,
    const int* __restrict__ rowptr, const int* __restrict__ eord,
    int N, float* __restrict__ env) {
  int t = blockIdx.x * 256 + threadIdx.x;
  if (t >= N * 32) return;
  int n = t >> 5, m = t & 31;
  int j0 = rowptr[n], j1 = rowptr[n + 1];
  float a0 = 0.f, a1 = 0.f, a2 = 0.f, a3 = 0.f;
  for (int j = j0; j < j1; ++j) {
    int e = eord[j];
    float w0 = b2f(wenv[(long)e*64 + 2*m]);
    float w1 = b2f(wenv[(long)e*64 + 2*m + 1]);
    float4 y = *reinterpret_cast<const float4*>(&Yb[(long)e*4]);
    a0 += w0;
    a1 += w1 * y.y;
    a2 += w1 * y.z;
    a3 += w1 * y.w;
  }
  *reinterpret_cast<float4*>(&env[(long)n*128 + m*4]) = make_float4(a0, a1, a2, a3);
}

// ---------------------------------------------------------------------------
// node gather (CSR) -> d_out
// ---------------------------------------------------------------------------
__global__ __launch_bounds__(256) void k_nodeg(
    const bf16* __restrict__ lat, const int* __restrict__ rowptr,
    const int* __restrict__ eord, int N, float* __restrict__ out) {
  int t = blockIdx.x * 256 + threadIdx.x;
  if (t >= N * 128) return;
  int n = t >> 7, j = t & 127;
  int j0 = rowptr[n], j1 = rowptr[n + 1];
  float s = 0.f;
  for (int q = j0; q < j1; ++q) {
    int e = eord[q];
    s += b2f(lat[(long)e*128 + j]);
  }
  out[t] = s * INV_SQRT_N;
}

// ---------------------------------------------------------------------------
// VALU GEMM (kept only for the 40->64 LATIN stage)
// ---------------------------------------------------------------------------
template<int K, int KC, int NOUT>
__global__ __launch_bounds__(256) void gemm_latin(
    const bf16* __restrict__ A2, const float* __restrict__ W,
    bf16* __restrict__ outb, const int* __restrict__ eidx,
    const float* __restrict__ nattr, float scale, int E) {
  constexpr int BM = 64;
  constexpr int BMP = BM + 1;
  constexpr int TN = NOUT / 16;
  __shared__ __align__(16) float As[KC * BMP];
  __shared__ __align__(16) float Bs[KC * NOUT];
  int tid = threadIdx.x;
  int tx = tid & 15, ty = tid >> 4;
  long e0 = (long)blockIdx.x * BM;
  float acc[4][TN];
  #pragma unroll
  for (int mm = 0; mm < 4; ++mm)
    #pragma unroll
    for (int nn = 0; nn < TN; ++nn) acc[mm][nn] = 0.f;

  for (int i = tid; i < BM * KC; i += 256) {
    int e = i / KC, k = i % KC;
    long eg = e0 + e;
    float v = 0.f;
    if (eg < E) {
      if (k < 16)       { int c = eidx[E + eg]; v = nattr[(long)c*16 + k]; }
      else if (k < 32)  { int s = eidx[eg];     v = nattr[(long)s*16 + k - 16]; }
      else              { v = b2f(A2[eg*8 + k - 32]); }
    }
    As[k * BMP + e] = v;
  }
  for (int i = tid; i < KC * NOUT; i += 256) {
    int k = i / NOUT, j = i % NOUT;
    Bs[i] = W[(long)k * NOUT + j];
  }
  __syncthreads();
  #pragma unroll
  for (int k = 0; k < KC; ++k) {
    float a[4];
    #pragma unroll
    for (int mm = 0; mm < 4; ++mm) a[mm] = As[k * BMP + ty*4 + mm];
    float b[TN];
    #pragma unroll
    for (int nn = 0; nn < TN; nn += 4) {
      float4 t = *reinterpret_cast<const float4*>(&Bs[k * NOUT + tx*TN + nn]);
      b[nn] = t.x; b[nn+1] = t.y; b[nn+2] = t.z; b[nn+3] = t.w;
    }
    #pragma unroll
    for (int mm = 0; mm < 4; ++mm)
      #pragma unroll
      for (int nn = 0; nn < TN; ++nn)
        acc[mm][nn] = fmaf(a[mm], b[nn], acc[mm][nn]);
  }
  #pragma unroll
  for (int mm = 0; mm < 4; ++mm) {
    long eg = e0 + ty*4 + mm;
    if (eg >= E) continue;
    #pragma unroll
    for (int nn = 0; nn < TN; ++nn)
      outb[eg * NOUT + tx*TN + nn] = f2b(silu_f(acc[mm][nn] * scale));
  }
}

// ---------------------------------------------------------------------------
// MFMA single-layer GEMM: 64 edges x NOUT, bf16 in, fp32 acc.
// A in [e][k] bf16; Wt pre-transposed bf16 [n][K].
// ---------------------------------------------------------------------------
template<int K, int NOUT, int EPI>
__global__ __launch_bounds__(256) void mgemm(
    const bf16* __restrict__ A, const unsigned short* __restrict__ Wt,
    bf16* __restrict__ out1, bf16* __restrict__ out2, float scale, int E) {
  constexpr int KP = 40;
  constexpr int CT = NOUT / 64;   // c-tiles per wave
  __shared__ __align__(16) unsigned short As[64 * KP];
  __shared__ __align__(16) unsigned short Bs[NOUT * KP];
  int tid = threadIdx.x;
  int lane = tid & 63, w = tid >> 6;
  int nl = lane & 15, quad = lane >> 4;
  long e0 = (long)blockIdx.x * 64;

  floatx4 acc[4][CT];
  #pragma unroll
  for (int i = 0; i < 4; ++i)
    #pragma unroll
    for (int j = 0; j < CT; ++j) acc[i][j] = (floatx4){0.f,0.f,0.f,0.f};

  int ae = tid & 63, akh = tid >> 6;
  long aeg = e0 + ae;

  for (int k0 = 0; k0 < K; k0 += 32) {
    if (k0) __syncthreads();
    { // stage A: 8 bf16 per thread, vector copy
      short8 v = {0,0,0,0,0,0,0,0};
      if (aeg < E) v = *(const short8*)(A + aeg * (long)K + k0 + akh * 8);
      *(short8*)&As[ae * KP + akh * 8] = v;
    }
    // stage B (transposed weights: contiguous k)
    if constexpr (NOUT == 128) {
      int j = tid >> 1, h = tid & 1;
      const short8* s = (const short8*)(Wt + (long)j * K + k0 + h * 16);
      *(short8*)&Bs[j * KP + h * 16]     = s[0];
      *(short8*)&Bs[j * KP + h * 16 + 8] = s[1];
    } else {
      int j = tid >> 2, h = tid & 3;
      *(short8*)&Bs[j * KP + h * 8] =
          *(const short8*)(Wt + (long)j * K + k0 + h * 8);
    }
    __syncthreads();
    short8 af[4], bv[CT];
    #pragma unroll
    for (int et = 0; et < 4; ++et)
      af[et] = *(const short8*)&As[(et*16 + nl) * KP + quad * 8];
    #pragma unroll
    for (int ct = 0; ct < CT; ++ct)
      bv[ct] = *(const short8*)&Bs[(w*CT*16 + ct*16 + nl) * KP + quad * 8];
    #pragma unroll
    for (int et = 0; et < 4; ++et)
      #pragma unroll
      for (int ct = 0; ct < CT; ++ct)
        acc[et][ct] = mfma16(af[et], bv[ct], acc[et][ct]);
  }

  // epilogue: C-layout col=lane&15, row=quad*4+reg  [m89-verified]
  #pragma unroll
  for (int et = 0; et < 4; ++et)
    #pragma unroll
    for (int ct = 0; ct < CT; ++ct)
      #pragma unroll
      for (int r = 0; r < 4; ++r) {
        long eg = e0 + et*16 + quad*4 + r;
        if (eg >= E) continue;
        int col = w*CT*16 + ct*16 + nl;
        float v = acc[et][ct][r] * scale;
        if constexpr (EPI == EPI_SPLIT) {
          if (col < 64) out1[eg * 64 + col] = f2b(v);
          else          out2[eg * 64 + (col - 64)] = f2b(v);
        } else { // EPI_STORE
          out1[eg * NOUT + col] = f2b(v);
        }
      }
}

// ---------------------------------------------------------------------------
// MFMA fused two-layer MLP: A(K) -> silu -> H(128 in LDS, bf16) -> @W1 -> epi
// ---------------------------------------------------------------------------
template<int K, int AMODE, int EPI>
__global__ __launch_bounds__(256) void mfused(
    const bf16* __restrict__ A, const bf16* __restrict__ A2,
    const unsigned short* __restrict__ W0t, const unsigned short* __restrict__ W1t,
    bf16* __restrict__ outb, const float* __restrict__ fcut,
    float scale0, float scale1, int E) {
  constexpr int KP = 40, HP = 136;
  __shared__ __align__(16) unsigned short As[64 * KP];
  __shared__ __align__(16) unsigned short Bs[128 * KP];
  __shared__ __align__(16) unsigned short Hs[64 * HP];
  int tid = threadIdx.x;
  int lane = tid & 63, w = tid >> 6;
  int nl = lane & 15, quad = lane >> 4;
  long e0 = (long)blockIdx.x * 64;

  floatx4 acc[4][2];
  #pragma unroll
  for (int i = 0; i < 4; ++i)
    #pragma unroll
    for (int j = 0; j < 2; ++j) acc[i][j] = (floatx4){0.f,0.f,0.f,0.f};

  int ae = tid & 63, akh = tid >> 6;
  long aeg = e0 + ae;
  int bj = tid >> 1, bh = tid & 1;

  // ---- layer 1 ----
  for (int k0 = 0; k0 < K; k0 += 32) {
    if (k0) __syncthreads();
    {
      int kk = k0 + akh * 8;
      short8 v = {0,0,0,0,0,0,0,0};
      if (aeg < E) {
        const bf16* src;
        if constexpr (AMODE == AMODE_PLAIN) src = A + aeg * (long)K + kk;
        else src = (kk < 128) ? (A + aeg * 128 + kk) : (A2 + aeg * 64 + (kk - 128));
        v = *(const short8*)src;
      }
      *(short8*)&As[ae * KP + akh * 8] = v;
    }
    {
      const short8* s = (const short8*)(W0t + (long)bj * K + k0 + bh * 16);
      *(short8*)&Bs[bj * KP + bh * 16]     = s[0];
      *(short8*)&Bs[bj * KP + bh * 16 + 8] = s[1];
    }
    __syncthreads();
    short8 af[4], bv[2];
    #pragma unroll
    for (int et = 0; et < 4; ++et)
      af[et] = *(const short8*)&As[(et*16 + nl) * KP + quad * 8];
    #pragma unroll
    for (int ct = 0; ct < 2; ++ct)
      bv[ct] = *(const short8*)&Bs[(w*32 + ct*16 + nl) * KP + quad * 8];
    #pragma unroll
    for (int et = 0; et < 4; ++et)
      #pragma unroll
      for (int ct = 0; ct < 2; ++ct)
        acc[et][ct] = mfma16(af[et], bv[ct], acc[et][ct]);
  }

  // silu -> Hs[e][h] bf16
  #pragma unroll
  for (int et = 0; et < 4; ++et)
    #pragma unroll
    for (int ct = 0; ct < 2; ++ct)
      #pragma unroll
      for (int r = 0; r < 4; ++r) {
        int el = et*16 + quad*4 + r;
        int h  = w*32 + ct*16 + nl;
        Hs[el * HP + h] = f2bu(silu_f(acc[et][ct][r] * scale0));
      }
  #pragma unroll
  for (int i = 0; i < 4; ++i)
    #pragma unroll
    for (int j = 0; j < 2; ++j) acc[i][j] = (floatx4){0.f,0.f,0.f,0.f};

  // ---- layer 2: 128 -> 128 ----
  for (int k0 = 0; k0 < 128; k0 += 32) {
    __syncthreads();   // Hs writes (iter 0) / previous Bs reads complete
    {
      const short8* s = (const short8*)(W1t + (long)bj * 128 + k0 + bh * 16);
      *(short8*)&Bs[bj * KP + bh * 16]     = s[0];
      *(short8*)&Bs[bj * KP + bh * 16 + 8] = s[1];
    }
    __syncthreads();
    short8 af[4], bv[2];
    #pragma unroll
    for (int et = 0; et < 4; ++et)
      af[et] = *(const short8*)&Hs[(et*16 + nl) * HP + k0 + quad * 8];
    #pragma unroll
    for (int ct = 0; ct < 2; ++ct)
      bv[ct] = *(const short8*)&Bs[(w*32 + ct*16 + nl) * KP + quad * 8];
    #pragma unroll
    for (int et = 0; et < 4; ++et)
      #pragma unroll
      for (int ct = 0; ct < 2; ++ct)
        acc[et][ct] = mfma16(af[et], bv[ct], acc[et][ct]);
  }

  // epilogue
  #pragma unroll
  for (int et = 0; et < 4; ++et)
    #pragma unroll
    for (int ct = 0; ct < 2; ++ct)
      #pragma unroll
      for (int r = 0; r < 4; ++r) {
        long eg = e0 + et*16 + quad*4 + r;
        if (eg >= E) continue;
        int col = w*32 + ct*16 + nl;
        float fc = fcut[eg];
        float v = acc[et][ct][r] * scale1 * fc;
        if constexpr (EPI == EPI_FCUT) {
          outb[eg * 128 + col] = f2b(v);
        } else { // EPI_RESID (in-place safe: block-private rows)
          long idx = eg * 128 + col;
          outb[idx] = f2b(C_OLD * b2f(outb[idx]) + C_NEW * v);
        }
      }
}

// ---------------------------------------------------------------------------
__global__ __launch_bounds__(256) void k_prod(
    const bf16* __restrict__ wedge, const float* __restrict__ env,
    const float* __restrict__ Yb, const int* __restrict__ eidx, int E,
    bf16* __restrict__ scal) {
  long t = (long)blockIdx.x * 256 + threadIdx.x;
  if (t >= (long)E * 32) return;
  long e = t >> 5;
  int m = (int)(t & 31);
  int c = eidx[E + e];
  float w0 = b2f(wedge[e*64 + 2*m]), w1 = b2f(wedge[e*64 + 2*m + 1]);
  const float* ep = env + (long)c*128 + m*4;
  float es  = ep[0] * INV_SQRT_N;
  float evx = ep[1] * INV_SQRT_N, evy = ep[2] * INV_SQRT_N, evz = ep[3] * INV_SQRT_N;
  float y1 = Yb[e*4+1], y2 = Yb[e*4+2], y3 = Yb[e*4+3];
  float fvx = w1*y1, fvy = w1*y2, fvz = w1*y3;
  scal[e*64 + m]      = f2b(w0 * es);
  scal[e*64 + 32 + m] = f2b((fvx*evx + fvy*evy + fvz*evz) * INV_SQRT3);
}

// ---------------------------------------------------------------------------
#define MIX_TE 8
__global__ __launch_bounds__(256) void k_mix(
    const bf16* __restrict__ wedge, const float* __restrict__ env,
    const float* __restrict__ env1, const float* __restrict__ Yb,
    const int* __restrict__ eidx, int E,
    const float* __restrict__ Ws0, const float* __restrict__ Wv0,
    bf16* __restrict__ scal) {
  __shared__ float P[MIX_TE * 32 * 13];
  __shared__ float E1s[MIX_TE * 32 * 5];
  __shared__ float WS[64 * 32];
  __shared__ float WV[96 * 32];
  int tid = threadIdx.x;
  for (int i = tid; i < 64*32; i += 256) WS[i] = Ws0[i];
  for (int i = tid; i < 96*32; i += 256) WV[i] = Wv0[i];
  int el = tid >> 5, m = tid & 31;
  long e = (long)blockIdx.x * MIX_TE + el;
  bool valid = (e < E);
  if (valid) {
    int c = eidx[E + e];
    float w0 = b2f(wedge[e*64 + 2*m]), w1 = b2f(wedge[e*64 + 2*m + 1]);
    const float* ep = env + (long)c*128 + m*4;
    float es  = ep[0] * INV_SQRT_N;
    float evx = ep[1] * INV_SQRT_N, evy = ep[2] * INV_SQRT_N, evz = ep[3] * INV_SQRT_N;
    float y1 = Yb[e*4+1], y2 = Yb[e*4+2], y3 = Yb[e*4+3];
    float fvx = w1*y1, fvy = w1*y2, fvz = w1*y3;
    float* p = &P[(el*32 + m) * 13];
    p[0]  = w0 * es;
    p[1]  = (fvx*evx + fvy*evy + fvz*evz) * INV_SQRT3;
    p[2]  = w0 * evx; p[3] = w0 * evy; p[4] = w0 * evz;
    p[5]  = fvx * es; p[6] = fvy * es; p[7] = fvz * es;
    p[8]  = (fvy*evz - fvz*evy) * INV_SQRT2;
    p[9]  = (fvz*evx - fvx*evz) * INV_SQRT2;
    p[10] = (fvx*evy - fvy*evx) * INV_SQRT2;
    const float* e1p = env1 + (long)c*128 + m*4;
    float* qd = &E1s[(el*32 + m) * 5];
    qd[0] = e1p[0]*INV_SQRT_N; qd[1] = e1p[1]*INV_SQRT_N;
    qd[2] = e1p[2]*INV_SQRT_N; qd[3] = e1p[3]*INV_SQRT_N;
  }
  __syncthreads();
  if (!valid) return;
  int o = m;
  float s = 0.f, v0 = 0.f, v1 = 0.f, v2 = 0.f;
  for (int mm = 0; mm < 32; ++mm) {
    const float* pp = &P[(el*32 + mm) * 13];
    float ws0 = WS[mm*32 + o], ws1 = WS[(32+mm)*32 + o];
    s = fmaf(pp[0], ws0, s); s = fmaf(pp[1], ws1, s);
    float wa = WV[mm*32 + o], wb = WV[(32+mm)*32 + o], wc = WV[(64+mm)*32 + o];
    v0 = fmaf(pp[2], wa, v0); v0 = fmaf(pp[5], wb, v0); v0 = fmaf(pp[8],  wc, v0);
    v1 = fmaf(pp[3], wa, v1); v1 = fmaf(pp[6], wb, v1); v1 = fmaf(pp[9],  wc, v1);
    v2 = fmaf(pp[4], wa, v2); v2 = fmaf(pp[7], wb, v2); v2 = fmaf(pp[10], wc, v2);
  }
  s  *= 0.125f;
  v0 *= 0.10206207261596577f;
  v1 *= 0.10206207261596577f;
  v2 *= 0.10206207261596577f;
  const float* qv = &E1s[(el*32 + o) * 5];
  float q0 = s * qv[0];
  float q1 = (v0*qv[1] + v1*qv[2] + v2*qv[3]) * INV_SQRT3;
  scal[e*64 + o]      = f2b(q0);
  scal[e*64 + 32 + o] = f2b(q1);
}

// ---------------------------------------------------------------------------
extern "C" void kernel_launch(void* const* d_in, const int* in_sizes, int n_in,
                              void* d_out, int out_size, void* d_ws, size_t ws_size,
                              hipStream_t stream) {
  const float* coords = (const float*)d_in[0];
  const float* nattr  = (const float*)d_in[1];
  const int*   eidx   = (const int*)d_in[2];
  const float* W2b0   = (const float*)d_in[3];
  const float* W2b1   = (const float*)d_in[4];
  const float* W2b2   = (const float*)d_in[5];
  const float* Wenv0  = (const float*)d_in[6];
  const float* Wlat0  = (const float*)d_in[7];
  const float* Wlat1  = (const float*)d_in[8];
  const float* Ws0    = (const float*)d_in[9];
  const float* Wv0    = (const float*)d_in[10];
  const float* Wenv1  = (const float*)d_in[11];
  const float* Wfin0  = (const float*)d_in[12];
  const float* Wfin1  = (const float*)d_in[13];
  float* out = (float*)d_out;
  int E = in_sizes[2] / 2;     // 320000
  int N = in_sizes[0] / 3;     // 10000

  // workspace carve (~182 MB): fp32, int (CSR), bf16, bf16 weights.
  float* fcut   = (float*)d_ws;                    // E
  float* Yb     = fcut + (size_t)E;                // 4E
  float* env    = Yb + (size_t)E*4;                // 128N
  float* env1   = env + (size_t)N*128;             // 128N
  int*   deg    = (int*)(env1 + (size_t)N*128);    // N
  int*   rowptr = deg + N;                         // N+8
  int*   cursor = rowptr + (N + 8);                // N
  int*   eord   = cursor + N;                      // E
  bf16*  b64    = (bf16*)(eord + E);               // 64E  (h64, then wedge)
  bf16*  lat    = b64 + (size_t)E*64;              // 128E
  bf16*  S      = lat + (size_t)E*128;             // 64E  (ef/wenv/scal0/wenv1/scal1)
  unsigned short* W2b1t  = (unsigned short*)(S + (size_t)E*64);  // 128x64
  unsigned short* W2b2t  = W2b1t + 128*64;        // 128x128
  unsigned short* Wenv0t = W2b2t + 128*128;       // 128x128
  unsigned short* Wlat0t = Wenv0t + 128*128;      // 128x192
  unsigned short* Wlat1t = Wlat0t + 128*192;      // 128x128
  unsigned short* Wenv1t = Wlat1t + 128*128;      // 64x128
  unsigned short* Wfin0t = Wenv1t + 64*128;       // 128x192
  unsigned short* Wfin1t = Wfin0t + 128*192;      // 128x128

  hipMemsetAsync(deg, 0, (size_t)N * sizeof(int), stream);

  dim3 blk(256);
  const float s40  = 0.15811388300841897f;  // 1/sqrt(40)
  const float s64  = 0.125f;
  const float s128 = 0.08838834764831845f;
  const float s192 = 0.07216878364870323f;
  int gB = (E + 63) / 64;
  int gE = (E + 255) / 256;

  // geometry + CSR + weight prep
  k_geom<<<gE, blk, 0, stream>>>(coords, eidx, E, fcut, Yb, S /*ef*/);
  k_deg<<<gE, blk, 0, stream>>>(eidx, E, deg);
  k_scan<<<1, 1024, 0, stream>>>(deg, N, rowptr, cursor);
  k_fill<<<gE, blk, 0, stream>>>(eidx, E, cursor, eord);
  k_wprep<<<(64*128 + 255)/256,  blk, 0, stream>>>(W2b1,  W2b1t,  64, 128);
  k_wprep<<<(128*128 + 255)/256, blk, 0, stream>>>(W2b2,  W2b2t,  128, 128);
  k_wprep<<<(128*128 + 255)/256, blk, 0, stream>>>(Wenv0, Wenv0t, 128, 128);
  k_wprep<<<(192*128 + 255)/256, blk, 0, stream>>>(Wlat0, Wlat0t, 192, 128);
  k_wprep<<<(128*128 + 255)/256, blk, 0, stream>>>(Wlat1, Wlat1t, 128, 128);
  k_wprep<<<(128*64 + 255)/256,  blk, 0, stream>>>(Wenv1, Wenv1t, 128, 64);
  k_wprep<<<(192*128 + 255)/256, blk, 0, stream>>>(Wfin0, Wfin0t, 192, 128);
  k_wprep<<<(128*128 + 255)/256, blk, 0, stream>>>(Wfin1, Wfin1t, 128, 128);

  // two-body MLP: 40 -> 64 silu (VALU) -> MFMA fused [64 -> 128 silu -> 128]*fcut
  gemm_latin<40,40,64><<<gB, blk, 0, stream>>>(
      S /*ef*/, W2b0, b64, eidx, nattr, s40, E);
  mfused<64,AMODE_PLAIN,EPI_FCUT><<<gB, blk, 0, stream>>>(
      b64, nullptr, W2b1t, W2b2t, lat, fcut, s64, s128, E);

  // Wenv0: w_edge -> b64, w_env -> S
  mgemm<128,128,EPI_SPLIT><<<gB, blk, 0, stream>>>(
      lat, Wenv0t, b64, S /*wenv*/, s128, E);

  // env = CSR gather
  k_envg<<<dim3((N*32 + 255) / 256), blk, 0, stream>>>(
      S /*wenv*/, Yb, rowptr, eord, N, env);

  // products -> scal0 (S reuse)
  k_prod<<<dim3((int)(((long)E*32 + 255) / 256)), blk, 0, stream>>>(
      b64, env, Yb, eidx, E, S /*scal0*/);

  // latent MLP (MFMA fused 192 -> 128 silu -> 128)*fcut, residual into lat
  mfused<192,AMODE_CONCAT,EPI_RESID><<<gB, blk, 0, stream>>>(
      lat, S /*scal0*/, Wlat0t, Wlat1t, lat, fcut, s192, s128, E);

  // Wenv1 -> wenv1 (S reuse)
  mgemm<128,64,EPI_STORE><<<gB, blk, 0, stream>>>(
      lat, Wenv1t, S /*wenv1*/, nullptr, s128, E);

  // env1 = CSR gather
  k_envg<<<dim3((N*32 + 255) / 256), blk, 0, stream>>>(
      S /*wenv1*/, Yb, rowptr, eord, N, env1);

  // mix -> scal1 (S reuse)
  k_mix<<<dim3((E + MIX_TE - 1) / MIX_TE), blk, 0, stream>>>(
      b64, env, env1, Yb, eidx, E, Ws0, Wv0, S /*scal1*/);

  // final MLP (MFMA fused) + residual, lat in place
  mfused<192,AMODE_CONCAT,EPI_RESID><<<gB, blk, 0, stream>>>(
      lat, S /*scal1*/, Wfin0t, Wfin1t, lat, fcut, s192, s128, E);

  // node segment-sum -> d_out
  k_nodeg<<<dim3((N*128 + 255) / 256), blk, 0, stream>>>(
      lat, rowptr, eord, N, out);
}

// Round 8
// 829.128 us; speedup vs baseline: 9.0267x; 1.4382x over previous
//
#include <hip/hip_runtime.h>
#include <hip/hip_bf16.h>
#include <math.h>

typedef __hip_bfloat16 bf16;
typedef __attribute__((ext_vector_type(8))) short short8;
typedef __attribute__((ext_vector_type(4))) float floatx4;

#define AMODE_PLAIN  0
#define AMODE_CONCAT 2
#define EPI_SPLIT    1
#define EPI_STORE    2
#define EPI_FCUT     3
#define EPI_RESID    4

#define INV_SQRT_N 0.17677669529663687f   /* 1/sqrt(32) */
#define INV_SQRT3  0.5773502691896258f
#define INV_SQRT2  0.7071067811865476f
#define C_OLD      0.8944271909999159f    /* 1/sqrt(1.25) */
#define C_NEW      0.4472135954999579f
#define PI_F       3.14159265358979323846f
#define SQRT3_F    1.7320508075688772f
#define BESSEL_PREF 0.6324555320336759f   /* sqrt(2/5) */

__device__ __forceinline__ float b2f(bf16 x) { return __bfloat162float(x); }
__device__ __forceinline__ bf16  f2b(float x) { return __float2bfloat16(x); }
__device__ __forceinline__ unsigned short f2bu(float x) {
  bf16 h = f2b(x); unsigned short u; __builtin_memcpy(&u, &h, 2); return u;
}
__device__ __forceinline__ float silu_f(float v) { return v / (1.f + __expf(-v)); }
__device__ __forceinline__ floatx4 mfma16(short8 a, short8 b, floatx4 c) {
  return __builtin_amdgcn_mfma_f32_16x16x32_bf16(a, b, c, 0, 0, 0);
}

// ---------------------------------------------------------------------------
// per-edge geometry + A40 row build: [nattr[c](16) | nattr[s](16) | ef(8)]
// ---------------------------------------------------------------------------
__global__ __launch_bounds__(256) void k_geom(
    const float* __restrict__ coords, const float* __restrict__ nattr,
    const int* __restrict__ eidx, int E,
    float* __restrict__ fcut, float* __restrict__ Yb, bf16* __restrict__ a40) {
  int e = blockIdx.x * 256 + threadIdx.x;
  if (e >= E) return;
  int s = eidx[e], c = eidx[E + e];
  float dx = coords[c*3+0] - coords[s*3+0];
  float dy = coords[c*3+1] - coords[s*3+1];
  float dz = coords[c*3+2] - coords[s*3+2];
  float r = sqrtf(dx*dx + dy*dy + dz*dz + 1e-12f);
  float u = r * 0.2f;
  float u3 = u*u*u;
  float u6 = u3*u3, u7 = u6*u, u8 = u7*u;
  float fc = 1.f - 28.f*u6 + 48.f*u7 - 21.f*u8;
  fc = (u < 1.f) ? fc : 0.f;
  float inv_r = 1.f / r;
  fcut[e] = fc;
  Yb[e*4+0] = 1.f;
  Yb[e*4+1] = SQRT3_F * dx * inv_r;
  Yb[e*4+2] = SQRT3_F * dy * inv_r;
  Yb[e*4+3] = SQRT3_F * dz * inv_r;
  bf16* row = a40 + (long)e * 40;
  #pragma unroll
  for (int i = 0; i < 16; ++i) row[i]      = f2b(nattr[(long)c*16 + i]);
  #pragma unroll
  for (int i = 0; i < 16; ++i) row[16 + i] = f2b(nattr[(long)s*16 + i]);
  float pref = BESSEL_PREF * inv_r * fc;
  #pragma unroll
  for (int n = 1; n <= 8; ++n)
    row[32 + n - 1] = f2b(pref * sinf((float)n * PI_F * u));
}

// ---------------------------------------------------------------------------
// CSR build
// ---------------------------------------------------------------------------
__global__ __launch_bounds__(256) void k_deg(
    const int* __restrict__ eidx, int E, int* __restrict__ deg) {
  int e = blockIdx.x * 256 + threadIdx.x;
  if (e < E) atomicAdd(&deg[eidx[E + e]], 1);
}

__global__ __launch_bounds__(1024) void k_scan(
    const int* __restrict__ deg, int N,
    int* __restrict__ rowptr, int* __restrict__ cursor) {
  __shared__ int part[1024];
  int t = threadIdx.x;
  int C = (N + 1023) / 1024;
  int base = t * C;
  int s = 0;
  for (int i = 0; i < C; ++i) { int idx = base + i; if (idx < N) s += deg[idx]; }
  part[t] = s;
  __syncthreads();
  for (int off = 1; off < 1024; off <<= 1) {
    int v = (t >= off) ? part[t - off] : 0;
    __syncthreads();
    part[t] += v;
    __syncthreads();
  }
  int excl = (t == 0) ? 0 : part[t - 1];
  for (int i = 0; i < C; ++i) {
    int idx = base + i;
    if (idx < N) { rowptr[idx] = excl; cursor[idx] = excl; excl += deg[idx]; }
  }
  if (t == 0) rowptr[N] = part[1023];
}

__global__ __launch_bounds__(256) void k_fill(
    const int* __restrict__ eidx, int E, int* __restrict__ cursor,
    int* __restrict__ eord) {
  int e = blockIdx.x * 256 + threadIdx.x;
  if (e >= E) return;
  int c = eidx[E + e];
  int slot = atomicAdd(&cursor[c], 1);
  eord[slot] = e;
}

// ---------------------------------------------------------------------------
// weight prep: fp32 W[k][n] -> bf16 Wt[n][k]
// ---------------------------------------------------------------------------
__global__ __launch_bounds__(256) void k_wprep(
    const float* __restrict__ W, unsigned short* __restrict__ Wt, int K, int NOUT) {
  int t = blockIdx.x * 256 + threadIdx.x;
  if (t >= K * NOUT) return;
  int n = t / K, k = t % K;
  Wt[n * K + k] = f2bu(W[k * NOUT + n]);
}

// combined mix weights: Wm[o][k], k<64 -> Ws0[k][o], k>=64 -> Wv0[k-64][o]
__global__ __launch_bounds__(256) void k_wmix(
    const float* __restrict__ Ws0, const float* __restrict__ Wv0,
    unsigned short* __restrict__ Wm) {
  int t = blockIdx.x * 256 + threadIdx.x;
  if (t >= 32 * 160) return;
  int o = t / 160, k = t % 160;
  float v = (k < 64) ? Ws0[k * 32 + o] : Wv0[(k - 64) * 32 + o];
  Wm[o * 160 + k] = f2bu(v);
}

// ---------------------------------------------------------------------------
// env gather (CSR)
// ---------------------------------------------------------------------------
__global__ __launch_bounds__(256) void k_envg(
    const bf16* __restrict__ wenv, const float* __restrict__ Yb,
    const int* __restrict__ rowptr, const int* __restrict__ eord,
    int N, float* __restrict__ env) {
  int t = blockIdx.x * 256 + threadIdx.x;
  if (t >= N * 32) return;
  int n = t >> 5, m = t & 31;
  int j0 = rowptr[n], j1 = rowptr[n + 1];
  float a0 = 0.f, a1 = 0.f, a2 = 0.f, a3 = 0.f;
  for (int j = j0; j < j1; ++j) {
    int e = eord[j];
    float w0 = b2f(wenv[(long)e*64 + 2*m]);
    float w1 = b2f(wenv[(long)e*64 + 2*m + 1]);
    float4 y = *reinterpret_cast<const float4*>(&Yb[(long)e*4]);
    a0 += w0;
    a1 += w1 * y.y;
    a2 += w1 * y.z;
    a3 += w1 * y.w;
  }
  *reinterpret_cast<float4*>(&env[(long)n*128 + m*4]) = make_float4(a0, a1, a2, a3);
}

// ---------------------------------------------------------------------------
// node gather (CSR) -> d_out
// ---------------------------------------------------------------------------
__global__ __launch_bounds__(256) void k_nodeg(
    const bf16* __restrict__ lat, const int* __restrict__ rowptr,
    const int* __restrict__ eord, int N, float* __restrict__ out) {
  int t = blockIdx.x * 256 + threadIdx.x;
  if (t >= N * 128) return;
  int n = t >> 7, j = t & 127;
  int j0 = rowptr[n], j1 = rowptr[n + 1];
  float s = 0.f;
  for (int q = j0; q < j1; ++q) {
    int e = eord[q];
    s += b2f(lat[(long)e*128 + j]);
  }
  out[t] = s * INV_SQRT_N;
}

// ---------------------------------------------------------------------------
// MFMA GEMM for the 40-wide two-body input (K padded 40->64 with zeros).
// ---------------------------------------------------------------------------
__global__ __launch_bounds__(256) void mgemm40(
    const bf16* __restrict__ A, const unsigned short* __restrict__ Wt,
    bf16* __restrict__ out, float scale, int E) {
  __shared__ __align__(16) unsigned short As[64 * 72];
  __shared__ __align__(16) unsigned short Bs[64 * 72];
  int tid = threadIdx.x;
  int lane = tid & 63, w = tid >> 6;
  int nl = lane & 15, quad = lane >> 4;
  long e0 = (long)blockIdx.x * 64;

  for (int i = tid; i < 512; i += 256) {
    int e = i >> 3, h = i & 7;
    short8 v = {0,0,0,0,0,0,0,0};
    long eg = e0 + e;
    if (h < 5 && eg < E) v = *(const short8*)(A + eg * 40 + h * 8);
    *(short8*)&As[e * 72 + h * 8] = v;
  }
  for (int i = tid; i < 512; i += 256) {
    int n = i >> 3, h = i & 7;
    short8 v = {0,0,0,0,0,0,0,0};
    if (h < 5) v = *(const short8*)(Wt + n * 40 + h * 8);
    *(short8*)&Bs[n * 72 + h * 8] = v;
  }
  __syncthreads();

  floatx4 acc[4];
  #pragma unroll
  for (int i = 0; i < 4; ++i) acc[i] = (floatx4){0.f,0.f,0.f,0.f};
  #pragma unroll
  for (int ks = 0; ks < 2; ++ks) {
    short8 af[4];
    #pragma unroll
    for (int et = 0; et < 4; ++et)
      af[et] = *(const short8*)&As[(et*16 + nl) * 72 + ks*32 + quad*8];
    short8 bv = *(const short8*)&Bs[(w*16 + nl) * 72 + ks*32 + quad*8];
    #pragma unroll
    for (int et = 0; et < 4; ++et) acc[et] = mfma16(af[et], bv, acc[et]);
  }
  #pragma unroll
  for (int et = 0; et < 4; ++et)
    #pragma unroll
    for (int r = 0; r < 4; ++r) {
      long eg = e0 + et*16 + quad*4 + r;
      if (eg >= E) continue;
      out[eg * 64 + w*16 + nl] = f2b(silu_f(acc[et][r] * scale));
    }
}

// ---------------------------------------------------------------------------
// MFMA single-layer GEMM: 64 edges x NOUT, A[e][K] bf16, Wt[n][K] bf16.
// ---------------------------------------------------------------------------
template<int K, int NOUT, int EPI>
__global__ __launch_bounds__(256) void mgemm(
    const bf16* __restrict__ A, const unsigned short* __restrict__ Wt,
    bf16* __restrict__ out1, bf16* __restrict__ out2, float scale, int E) {
  constexpr int KP = 40;
  constexpr int CT = NOUT / 64;
  __shared__ __align__(16) unsigned short As[64 * KP];
  __shared__ __align__(16) unsigned short Bs[NOUT * KP];
  int tid = threadIdx.x;
  int lane = tid & 63, w = tid >> 6;
  int nl = lane & 15, quad = lane >> 4;
  long e0 = (long)blockIdx.x * 64;

  floatx4 acc[4][CT];
  #pragma unroll
  for (int i = 0; i < 4; ++i)
    #pragma unroll
    for (int j = 0; j < CT; ++j) acc[i][j] = (floatx4){0.f,0.f,0.f,0.f};

  int ae = tid & 63, akh = tid >> 6;
  long aeg = e0 + ae;

  for (int k0 = 0; k0 < K; k0 += 32) {
    if (k0) __syncthreads();
    {
      short8 v = {0,0,0,0,0,0,0,0};
      if (aeg < E) v = *(const short8*)(A + aeg * (long)K + k0 + akh * 8);
      *(short8*)&As[ae * KP + akh * 8] = v;
    }
    if constexpr (NOUT == 128) {
      int j = tid >> 1, h = tid & 1;
      const short8* s = (const short8*)(Wt + (long)j * K + k0 + h * 16);
      *(short8*)&Bs[j * KP + h * 16]     = s[0];
      *(short8*)&Bs[j * KP + h * 16 + 8] = s[1];
    } else {
      int j = tid >> 2, h = tid & 3;
      *(short8*)&Bs[j * KP + h * 8] =
          *(const short8*)(Wt + (long)j * K + k0 + h * 8);
    }
    __syncthreads();
    short8 af[4], bv[CT];
    #pragma unroll
    for (int et = 0; et < 4; ++et)
      af[et] = *(const short8*)&As[(et*16 + nl) * KP + quad * 8];
    #pragma unroll
    for (int ct = 0; ct < CT; ++ct)
      bv[ct] = *(const short8*)&Bs[(w*CT*16 + ct*16 + nl) * KP + quad * 8];
    #pragma unroll
    for (int et = 0; et < 4; ++et)
      #pragma unroll
      for (int ct = 0; ct < CT; ++ct)
        acc[et][ct] = mfma16(af[et], bv[ct], acc[et][ct]);
  }

  #pragma unroll
  for (int et = 0; et < 4; ++et)
    #pragma unroll
    for (int ct = 0; ct < CT; ++ct)
      #pragma unroll
      for (int r = 0; r < 4; ++r) {
        long eg = e0 + et*16 + quad*4 + r;
        if (eg >= E) continue;
        int col = w*CT*16 + ct*16 + nl;
        float v = acc[et][ct][r] * scale;
        if constexpr (EPI == EPI_SPLIT) {
          if (col < 64) out1[eg * 64 + col] = f2b(v);
          else          out2[eg * 64 + (col - 64)] = f2b(v);
        } else { // EPI_STORE
          out1[eg * NOUT + col] = f2b(v);
        }
      }
}

// ---------------------------------------------------------------------------
// MFMA fused two-layer MLP: A(K) -> silu -> H(128, LDS bf16) -> @W1 -> epi
// ---------------------------------------------------------------------------
template<int K, int AMODE, int EPI>
__global__ __launch_bounds__(256) void mfused(
    const bf16* __restrict__ A, const bf16* __restrict__ A2,
    const unsigned short* __restrict__ W0t, const unsigned short* __restrict__ W1t,
    bf16* __restrict__ outb, const float* __restrict__ fcut,
    float scale0, float scale1, int E) {
  constexpr int KP = 40, HP = 136;
  __shared__ __align__(16) unsigned short As[64 * KP];
  __shared__ __align__(16) unsigned short Bs[128 * KP];
  __shared__ __align__(16) unsigned short Hs[64 * HP];
  int tid = threadIdx.x;
  int lane = tid & 63, w = tid >> 6;
  int nl = lane & 15, quad = lane >> 4;
  long e0 = (long)blockIdx.x * 64;

  floatx4 acc[4][2];
  #pragma unroll
  for (int i = 0; i < 4; ++i)
    #pragma unroll
    for (int j = 0; j < 2; ++j) acc[i][j] = (floatx4){0.f,0.f,0.f,0.f};

  int ae = tid & 63, akh = tid >> 6;
  long aeg = e0 + ae;
  int bj = tid >> 1, bh = tid & 1;

  for (int k0 = 0; k0 < K; k0 += 32) {
    if (k0) __syncthreads();
    {
      int kk = k0 + akh * 8;
      short8 v = {0,0,0,0,0,0,0,0};
      if (aeg < E) {
        const bf16* src;
        if constexpr (AMODE == AMODE_PLAIN) src = A + aeg * (long)K + kk;
        else src = (kk < 128) ? (A + aeg * 128 + kk) : (A2 + aeg * 64 + (kk - 128));
        v = *(const short8*)src;
      }
      *(short8*)&As[ae * KP + akh * 8] = v;
    }
    {
      const short8* s = (const short8*)(W0t + (long)bj * K + k0 + bh * 16);
      *(short8*)&Bs[bj * KP + bh * 16]     = s[0];
      *(short8*)&Bs[bj * KP + bh * 16 + 8] = s[1];
    }
    __syncthreads();
    short8 af[4], bv[2];
    #pragma unroll
    for (int et = 0; et < 4; ++et)
      af[et] = *(const short8*)&As[(et*16 + nl) * KP + quad * 8];
    #pragma unroll
    for (int ct = 0; ct < 2; ++ct)
      bv[ct] = *(const short8*)&Bs[(w*32 + ct*16 + nl) * KP + quad * 8];
    #pragma unroll
    for (int et = 0; et < 4; ++et)
      #pragma unroll
      for (int ct = 0; ct < 2; ++ct)
        acc[et][ct] = mfma16(af[et], bv[ct], acc[et][ct]);
  }

  #pragma unroll
  for (int et = 0; et < 4; ++et)
    #pragma unroll
    for (int ct = 0; ct < 2; ++ct)
      #pragma unroll
      for (int r = 0; r < 4; ++r) {
        int el = et*16 + quad*4 + r;
        int h  = w*32 + ct*16 + nl;
        Hs[el * HP + h] = f2bu(silu_f(acc[et][ct][r] * scale0));
      }
  #pragma unroll
  for (int i = 0; i < 4; ++i)
    #pragma unroll
    for (int j = 0; j < 2; ++j) acc[i][j] = (floatx4){0.f,0.f,0.f,0.f};

  for (int k0 = 0; k0 < 128; k0 += 32) {
    __syncthreads();
    {
      const short8* s = (const short8*)(W1t + (long)bj * 128 + k0 + bh * 16);
      *(short8*)&Bs[bj * KP + bh * 16]     = s[0];
      *(short8*)&Bs[bj * KP + bh * 16 + 8] = s[1];
    }
    __syncthreads();
    short8 af[4], bv[2];
    #pragma unroll
    for (int et = 0; et < 4; ++et)
      af[et] = *(const short8*)&Hs[(et*16 + nl) * HP + k0 + quad * 8];
    #pragma unroll
    for (int ct = 0; ct < 2; ++ct)
      bv[ct] = *(const short8*)&Bs[(w*32 + ct*16 + nl) * KP + quad * 8];
    #pragma unroll
    for (int et = 0; et < 4; ++et)
      #pragma unroll
      for (int ct = 0; ct < 2; ++ct)
        acc[et][ct] = mfma16(af[et], bv[ct], acc[et][ct]);
  }

  #pragma unroll
  for (int et = 0; et < 4; ++et)
    #pragma unroll
    for (int ct = 0; ct < 2; ++ct)
      #pragma unroll
      for (int r = 0; r < 4; ++r) {
        long eg = e0 + et*16 + quad*4 + r;
        if (eg >= E) continue;
        int col = w*32 + ct*16 + nl;
        float fc = fcut[eg];
        float v = acc[et][ct][r] * scale1 * fc;
        if constexpr (EPI == EPI_FCUT) {
          outb[eg * 128 + col] = f2b(v);
        } else { // EPI_RESID
          long idx = eg * 128 + col;
          outb[idx] = f2b(C_OLD * b2f(outb[idx]) + C_NEW * v);
        }
      }
}

// ---------------------------------------------------------------------------
// products -> scal0 = [p0 | p1]
// ---------------------------------------------------------------------------
__global__ __launch_bounds__(256) void k_prod(
    const bf16* __restrict__ wedge, const float* __restrict__ env,
    const float* __restrict__ Yb, const int* __restrict__ eidx, int E,
    bf16* __restrict__ scal) {
  long t = (long)blockIdx.x * 256 + threadIdx.x;
  if (t >= (long)E * 32) return;
  long e = t >> 5;
  int m = (int)(t & 31);
  int c = eidx[E + e];
  float w0 = b2f(wedge[e*64 + 2*m]), w1 = b2f(wedge[e*64 + 2*m + 1]);
  const float* ep = env + (long)c*128 + m*4;
  float es  = ep[0] * INV_SQRT_N;
  float evx = ep[1] * INV_SQRT_N, evy = ep[2] * INV_SQRT_N, evz = ep[3] * INV_SQRT_N;
  float y1 = Yb[e*4+1], y2 = Yb[e*4+2], y3 = Yb[e*4+3];
  float fvx = w1*y1, fvy = w1*y2, fvz = w1*y3;
  scal[e*64 + m]      = f2b(w0 * es);
  scal[e*64 + 32 + m] = f2b((fvx*evx + fvy*evy + fvz*evz) * INV_SQRT3);
}

// ---------------------------------------------------------------------------
// MFMA mix: per 64-edge block, products -> LDS, 4 wave-jobs
// (s_mix K=64, v_mix xyz K=96), combine with env1 -> scal1.
// ---------------------------------------------------------------------------
__global__ __launch_bounds__(256) void k_mix2(
    const bf16* __restrict__ wedge, const float* __restrict__ env,
    const float* __restrict__ env1, const float* __restrict__ Yb,
    const int* __restrict__ eidx, const unsigned short* __restrict__ Wm,
    int E, bf16* __restrict__ scal) {
  constexpr int PP = 360;   // P stride (shorts): 2-way bank alias only
  constexpr int RP = 132;   // R stride (floats)
  __shared__ __align__(16) unsigned char SB[64 * PP * 2];  // P (bf16) / R (fp32)
  __shared__ __align__(16) unsigned short Wl[32 * 160];
  unsigned short* P = (unsigned short*)SB;
  float* R = (float*)SB;
  int tid = threadIdx.x;
  int lane = tid & 63, w = tid >> 6;
  int nl = lane & 15, quad = lane >> 4;
  long e0 = (long)blockIdx.x * 64;

  // stage combined weights (5120 shorts = 640 short8)
  for (int i = tid; i < 640; i += 256)
    *(short8*)&Wl[i * 8] = *(const short8*)(Wm + i * 8);

  // phase 1: per-(edge,m) products into P
  int m = tid & 31;
  #pragma unroll
  for (int it = 0; it < 8; ++it) {
    int el = (tid >> 5) + it * 8;
    long e = e0 + el;
    if (e < E) {
      int c = eidx[E + e];
      float w0 = b2f(wedge[e*64 + 2*m]), w1 = b2f(wedge[e*64 + 2*m + 1]);
      float4 ev4 = *(const float4*)(env + (long)c*128 + m*4);
      float4 y   = *(const float4*)(Yb + e*4);
      float es  = ev4.x * INV_SQRT_N;
      float evx = ev4.y * INV_SQRT_N, evy = ev4.z * INV_SQRT_N, evz = ev4.w * INV_SQRT_N;
      float fvx = w1*y.y, fvy = w1*y.z, fvz = w1*y.w;
      unsigned short* p = P + el * PP;
      p[m]       = f2bu(w0 * es);
      p[32 + m]  = f2bu((fvx*evx + fvy*evy + fvz*evz) * INV_SQRT3);
      p[64 + m]  = f2bu(w0 * evx);                        // p2x
      p[96 + m]  = f2bu(fvx * es);                        // p3x
      p[128 + m] = f2bu((fvy*evz - fvz*evy) * INV_SQRT2); // p4x
      p[160 + m] = f2bu(w0 * evy);
      p[192 + m] = f2bu(fvy * es);
      p[224 + m] = f2bu((fvz*evx - fvx*evz) * INV_SQRT2);
      p[256 + m] = f2bu(w0 * evz);
      p[288 + m] = f2bu(fvz * es);
      p[320 + m] = f2bu((fvx*evy - fvy*evx) * INV_SQRT2);
    } else {
      unsigned short* p = P + el * PP;
      #pragma unroll
      for (int q = 0; q < 11; ++q) p[q*32 + m] = 0;
    }
  }
  __syncthreads();

  // phase 2: wave w = job w (0: s_mix K=64; 1..3: v_mix xyz K=96)
  floatx4 acc[4][2];
  #pragma unroll
  for (int i = 0; i < 4; ++i)
    #pragma unroll
    for (int j = 0; j < 2; ++j) acc[i][j] = (floatx4){0.f,0.f,0.f,0.f};
  int pbase  = (w == 0) ? 0 : 64 + (w - 1) * 96;
  int wkbase = (w == 0) ? 0 : 64;
  int ksteps = (w == 0) ? 2 : 3;
  for (int ks = 0; ks < ksteps; ++ks) {
    short8 af[4], bv[2];
    #pragma unroll
    for (int et = 0; et < 4; ++et)
      af[et] = *(const short8*)&P[(et*16 + nl) * PP + pbase + ks*32 + quad*8];
    #pragma unroll
    for (int ct = 0; ct < 2; ++ct)
      bv[ct] = *(const short8*)&Wl[(ct*16 + nl) * 160 + wkbase + ks*32 + quad*8];
    #pragma unroll
    for (int et = 0; et < 4; ++et)
      #pragma unroll
      for (int ct = 0; ct < 2; ++ct)
        acc[et][ct] = mfma16(af[et], bv[ct], acc[et][ct]);
  }
  __syncthreads();   // P reads complete before overwrite as R

  #pragma unroll
  for (int et = 0; et < 4; ++et)
    #pragma unroll
    for (int ct = 0; ct < 2; ++ct)
      #pragma unroll
      for (int r = 0; r < 4; ++r) {
        int el = et*16 + quad*4 + r;
        R[el * RP + w*32 + ct*16 + nl] = acc[et][ct][r];
      }
  __syncthreads();

  // final: combine with env1 -> scal1
  #pragma unroll
  for (int it = 0; it < 8; ++it) {
    int el = (tid >> 5) + it * 8;
    long e = e0 + el;
    if (e >= E) continue;
    int o = m;
    int c = eidx[E + e];
    float4 e1 = *(const float4*)(env1 + (long)c*128 + o*4);
    float sr = R[el * RP + o];
    float vx = R[el * RP + 32 + o];
    float vy = R[el * RP + 64 + o];
    float vz = R[el * RP + 96 + o];
    float q0 = sr * 0.125f * (e1.x * INV_SQRT_N);
    float q1 = (vx*e1.y + vy*e1.z + vz*e1.w) *
               (0.10206207261596577f * INV_SQRT_N * INV_SQRT3);
    scal[e*64 + o]      = f2b(q0);
    scal[e*64 + 32 + o] = f2b(q1);
  }
}

// ---------------------------------------------------------------------------
extern "C" void kernel_launch(void* const* d_in, const int* in_sizes, int n_in,
                              void* d_out, int out_size, void* d_ws, size_t ws_size,
                              hipStream_t stream) {
  const float* coords = (const float*)d_in[0];
  const float* nattr  = (const float*)d_in[1];
  const int*   eidx   = (const int*)d_in[2];
  const float* W2b0   = (const float*)d_in[3];
  const float* W2b1   = (const float*)d_in[4];
  const float* W2b2   = (const float*)d_in[5];
  const float* Wenv0  = (const float*)d_in[6];
  const float* Wlat0  = (const float*)d_in[7];
  const float* Wlat1  = (const float*)d_in[8];
  const float* Ws0    = (const float*)d_in[9];
  const float* Wv0    = (const float*)d_in[10];
  const float* Wenv1  = (const float*)d_in[11];
  const float* Wfin0  = (const float*)d_in[12];
  const float* Wfin1  = (const float*)d_in[13];
  float* out = (float*)d_out;
  int E = in_sizes[2] / 2;     // 320000
  int N = in_sizes[0] / 3;     // 10000

  // workspace carve (~182 MB)
  float* fcut   = (float*)d_ws;                    // E
  float* Yb     = fcut + (size_t)E;                // 4E
  float* env    = Yb + (size_t)E*4;                // 128N
  float* env1   = env + (size_t)N*128;             // 128N
  int*   deg    = (int*)(env1 + (size_t)N*128);    // N
  int*   rowptr = deg + N;                         // N+8
  int*   cursor = rowptr + (N + 8);                // N
  int*   eord   = cursor + N;                      // E
  bf16*  b64    = (bf16*)(eord + E);               // 64E (h64, then wedge)
  bf16*  lat    = b64 + (size_t)E*64;              // 128E
  bf16*  S      = lat + (size_t)E*128;             // 64E (a40/wenv/scal0/wenv1/scal1)
  unsigned short* W2b1t  = (unsigned short*)(S + (size_t)E*64);  // 128x64
  unsigned short* W2b2t  = W2b1t + 128*64;        // 128x128
  unsigned short* Wenv0t = W2b2t + 128*128;       // 128x128
  unsigned short* Wlat0t = Wenv0t + 128*128;      // 128x192
  unsigned short* Wlat1t = Wlat0t + 128*192;      // 128x128
  unsigned short* Wenv1t = Wlat1t + 128*128;      // 64x128
  unsigned short* Wfin0t = Wenv1t + 64*128;       // 128x192
  unsigned short* Wfin1t = Wfin0t + 128*192;      // 128x128
  unsigned short* W2b0t  = Wfin1t + 128*128;      // 64x40
  unsigned short* Wmixt  = W2b0t + 64*40;         // 32x160

  hipMemsetAsync(deg, 0, (size_t)N * sizeof(int), stream);

  dim3 blk(256);
  const float s40  = 0.15811388300841897f;  // 1/sqrt(40)
  const float s64  = 0.125f;
  const float s128 = 0.08838834764831845f;
  const float s192 = 0.07216878364870323f;
  int gB = (E + 63) / 64;
  int gE = (E + 255) / 256;

  // geometry (+A40 build into S) + CSR + weight prep
  k_geom<<<gE, blk, 0, stream>>>(coords, nattr, eidx, E, fcut, Yb, S /*a40*/);
  k_deg<<<gE, blk, 0, stream>>>(eidx, E, deg);
  k_scan<<<1, 1024, 0, stream>>>(deg, N, rowptr, cursor);
  k_fill<<<gE, blk, 0, stream>>>(eidx, E, cursor, eord);
  k_wprep<<<(64*128 + 255)/256,  blk, 0, stream>>>(W2b1,  W2b1t,  64, 128);
  k_wprep<<<(128*128 + 255)/256, blk, 0, stream>>>(W2b2,  W2b2t,  128, 128);
  k_wprep<<<(128*128 + 255)/256, blk, 0, stream>>>(Wenv0, Wenv0t, 128, 128);
  k_wprep<<<(192*128 + 255)/256, blk, 0, stream>>>(Wlat0, Wlat0t, 192, 128);
  k_wprep<<<(128*128 + 255)/256, blk, 0, stream>>>(Wlat1, Wlat1t, 128, 128);
  k_wprep<<<(128*64 + 255)/256,  blk, 0, stream>>>(Wenv1, Wenv1t, 128, 64);
  k_wprep<<<(192*128 + 255)/256, blk, 0, stream>>>(Wfin0, Wfin0t, 192, 128);
  k_wprep<<<(128*128 + 255)/256, blk, 0, stream>>>(Wfin1, Wfin1t, 128, 128);
  k_wprep<<<(40*64 + 255)/256,   blk, 0, stream>>>(W2b0,  W2b0t,  40, 64);
  k_wmix<<<(32*160 + 255)/256,   blk, 0, stream>>>(Ws0, Wv0, Wmixt);

  // two-body MLP: MFMA 40->64 silu, then MFMA fused [64->128 silu ->128]*fcut
  mgemm40<<<gB, blk, 0, stream>>>(S /*a40*/, W2b0t, b64, s40, E);
  mfused<64,AMODE_PLAIN,EPI_FCUT><<<gB, blk, 0, stream>>>(
      b64, nullptr, W2b1t, W2b2t, lat, fcut, s64, s128, E);

  // Wenv0: w_edge -> b64, w_env -> S
  mgemm<128,128,EPI_SPLIT><<<gB, blk, 0, stream>>>(
      lat, Wenv0t, b64, S /*wenv*/, s128, E);

  // env = CSR gather
  k_envg<<<dim3((N*32 + 255) / 256), blk, 0, stream>>>(
      S /*wenv*/, Yb, rowptr, eord, N, env);

  // products -> scal0 (S reuse)
  k_prod<<<dim3((int)(((long)E*32 + 255) / 256)), blk, 0, stream>>>(
      b64, env, Yb, eidx, E, S /*scal0*/);

  // latent MLP (MFMA fused 192->128 silu ->128)*fcut, residual into lat
  mfused<192,AMODE_CONCAT,EPI_RESID><<<gB, blk, 0, stream>>>(
      lat, S /*scal0*/, Wlat0t, Wlat1t, lat, fcut, s192, s128, E);

  // Wenv1 -> wenv1 (S reuse)
  mgemm<128,64,EPI_STORE><<<gB, blk, 0, stream>>>(
      lat, Wenv1t, S /*wenv1*/, nullptr, s128, E);

  // env1 = CSR gather
  k_envg<<<dim3((N*32 + 255) / 256), blk, 0, stream>>>(
      S /*wenv1*/, Yb, rowptr, eord, N, env1);

  // MFMA mix -> scal1 (S reuse)
  k_mix2<<<gB, blk, 0, stream>>>(
      b64, env, env1, Yb, eidx, Wmixt, E, S /*scal1*/);

  // final MLP (MFMA fused) + residual, lat in place
  mfused<192,AMODE_CONCAT,EPI_RESID><<<gB, blk, 0, stream>>>(
      lat, S /*scal1*/, Wfin0t, Wfin1t, lat, fcut, s192, s128, E);

  // node segment-sum -> d_out
  k_nodeg<<<dim3((N*128 + 255) / 256), blk, 0, stream>>>(
      lat, rowptr, eord, N, out);
}

// Round 9
// 724.054 us; speedup vs baseline: 10.3366x; 1.1451x over previous
//
#include <hip/hip_runtime.h>
#include <hip/hip_bf16.h>
#include <math.h>

typedef __hip_bfloat16 bf16;
typedef __attribute__((ext_vector_type(8))) short short8;
typedef __attribute__((ext_vector_type(4))) float floatx4;

#define AMODE_PLAIN  0
#define AMODE_CONCAT 2
#define EPI_SPLIT    1
#define EPI_STORE    2
#define EPI_FCUT     3
#define EPI_RESID    4

#define INV_SQRT_N 0.17677669529663687f   /* 1/sqrt(32) */
#define INV_SQRT3  0.5773502691896258f
#define INV_SQRT2  0.7071067811865476f
#define C_OLD      0.8944271909999159f    /* 1/sqrt(1.25) */
#define C_NEW      0.4472135954999579f
#define PI_F       3.14159265358979323846f
#define SQRT3_F    1.7320508075688772f
#define BESSEL_PREF 0.6324555320336759f   /* sqrt(2/5) */

__device__ __forceinline__ float b2f(bf16 x) { return __bfloat162float(x); }
__device__ __forceinline__ bf16  f2b(float x) { return __float2bfloat16(x); }
__device__ __forceinline__ unsigned short f2bu(float x) {
  bf16 h = f2b(x); unsigned short u; __builtin_memcpy(&u, &h, 2); return u;
}
__device__ __forceinline__ float silu_f(float v) { return v / (1.f + __expf(-v)); }
__device__ __forceinline__ floatx4 mfma16(short8 a, short8 b, floatx4 c) {
  return __builtin_amdgcn_mfma_f32_16x16x32_bf16(a, b, c, 0, 0, 0);
}

// ---------------------------------------------------------------------------
// CSR build: deg -> rowptr/cursor -> slot assignment (+cent per slot)
// ---------------------------------------------------------------------------
__global__ __launch_bounds__(256) void k_deg(
    const int* __restrict__ eidx, int E, int* __restrict__ deg) {
  int e = blockIdx.x * 256 + threadIdx.x;
  if (e < E) atomicAdd(&deg[eidx[E + e]], 1);
}

__global__ __launch_bounds__(1024) void k_scan(
    const int* __restrict__ deg, int N,
    int* __restrict__ rowptr, int* __restrict__ cursor) {
  __shared__ int part[1024];
  int t = threadIdx.x;
  int C = (N + 1023) / 1024;
  int base = t * C;
  int s = 0;
  for (int i = 0; i < C; ++i) { int idx = base + i; if (idx < N) s += deg[idx]; }
  part[t] = s;
  __syncthreads();
  for (int off = 1; off < 1024; off <<= 1) {
    int v = (t >= off) ? part[t - off] : 0;
    __syncthreads();
    part[t] += v;
    __syncthreads();
  }
  int excl = (t == 0) ? 0 : part[t - 1];
  for (int i = 0; i < C; ++i) {
    int idx = base + i;
    if (idx < N) { rowptr[idx] = excl; cursor[idx] = excl; excl += deg[idx]; }
  }
  if (t == 0) rowptr[N] = part[1023];
}

__global__ __launch_bounds__(256) void k_fill(
    const int* __restrict__ eidx, int E, int* __restrict__ cursor,
    int* __restrict__ eord, int* __restrict__ cent) {
  int e = blockIdx.x * 256 + threadIdx.x;
  if (e >= E) return;
  int c = eidx[E + e];
  int slot = atomicAdd(&cursor[c], 1);
  eord[slot] = e;
  cent[slot] = c;
}

// ---------------------------------------------------------------------------
// per-slot geometry + A40 row build: [nattr[c](16) | nattr[s](16) | ef(8)]
// Runs AFTER CSR build; slot j <- edge eord[j]. All per-edge arrays live in
// slot space from here on (edges grouped by center -> L1-local env reads,
// sequential CSR gathers).
// ---------------------------------------------------------------------------
__global__ __launch_bounds__(256) void k_geom(
    const float* __restrict__ coords, const float* __restrict__ nattr,
    const int* __restrict__ eidx, const int* __restrict__ eord, int E,
    float* __restrict__ fcut, float* __restrict__ Yb, bf16* __restrict__ a40) {
  int j = blockIdx.x * 256 + threadIdx.x;
  if (j >= E) return;
  int e = eord[j];
  int s = eidx[e], c = eidx[E + e];
  float dx = coords[c*3+0] - coords[s*3+0];
  float dy = coords[c*3+1] - coords[s*3+1];
  float dz = coords[c*3+2] - coords[s*3+2];
  float r = sqrtf(dx*dx + dy*dy + dz*dz + 1e-12f);
  float u = r * 0.2f;
  float u3 = u*u*u;
  float u6 = u3*u3, u7 = u6*u, u8 = u7*u;
  float fc = 1.f - 28.f*u6 + 48.f*u7 - 21.f*u8;
  fc = (u < 1.f) ? fc : 0.f;
  float inv_r = 1.f / r;
  fcut[j] = fc;
  Yb[j*4+0] = 1.f;
  Yb[j*4+1] = SQRT3_F * dx * inv_r;
  Yb[j*4+2] = SQRT3_F * dy * inv_r;
  Yb[j*4+3] = SQRT3_F * dz * inv_r;
  bf16* row = a40 + (long)j * 40;
  #pragma unroll
  for (int i = 0; i < 16; ++i) row[i]      = f2b(nattr[(long)c*16 + i]);
  #pragma unroll
  for (int i = 0; i < 16; ++i) row[16 + i] = f2b(nattr[(long)s*16 + i]);
  float pref = BESSEL_PREF * inv_r * fc;
  #pragma unroll
  for (int n = 1; n <= 8; ++n)
    row[32 + n - 1] = f2b(pref * sinf((float)n * PI_F * u));
}

// ---------------------------------------------------------------------------
// merged weight prep: all fp32 W[k][n] -> bf16 Wt[n][k] (+ combined mix W)
// ---------------------------------------------------------------------------
__device__ __forceinline__ void wp(const float* W, unsigned short* Wt,
                                   int K, int NOUT, int t) {
  int n = t / K, k = t % K;
  Wt[n * K + k] = f2bu(W[k * NOUT + n]);
}

__global__ __launch_bounds__(256) void k_wprep_all(
    const float* W2b0, const float* W2b1, const float* W2b2,
    const float* Wenv0, const float* Wlat0, const float* Wlat1,
    const float* Wenv1, const float* Wfin0, const float* Wfin1,
    const float* Ws0, const float* Wv0,
    unsigned short* W2b0t, unsigned short* W2b1t, unsigned short* W2b2t,
    unsigned short* Wenv0t, unsigned short* Wlat0t, unsigned short* Wlat1t,
    unsigned short* Wenv1t, unsigned short* Wfin0t, unsigned short* Wfin1t,
    unsigned short* Wmixt) {
  int t = blockIdx.x * 256 + threadIdx.x;
  if (t < 8192)  { wp(W2b1,  W2b1t,  64, 128, t); return; } t -= 8192;
  if (t < 16384) { wp(W2b2,  W2b2t, 128, 128, t); return; } t -= 16384;
  if (t < 16384) { wp(Wenv0, Wenv0t,128, 128, t); return; } t -= 16384;
  if (t < 24576) { wp(Wlat0, Wlat0t,192, 128, t); return; } t -= 24576;
  if (t < 16384) { wp(Wlat1, Wlat1t,128, 128, t); return; } t -= 16384;
  if (t < 8192)  { wp(Wenv1, Wenv1t,128,  64, t); return; } t -= 8192;
  if (t < 24576) { wp(Wfin0, Wfin0t,192, 128, t); return; } t -= 24576;
  if (t < 16384) { wp(Wfin1, Wfin1t,128, 128, t); return; } t -= 16384;
  if (t < 2560)  { wp(W2b0,  W2b0t,  40,  64, t); return; } t -= 2560;
  if (t < 5120) {
    int o = t / 160, k = t % 160;
    float v = (k < 64) ? Ws0[k * 32 + o] : Wv0[(k - 64) * 32 + o];
    Wmixt[o * 160 + k] = f2bu(v);
  }
}

// ---------------------------------------------------------------------------
// env gather (CSR, slot-ordered: fully sequential reads)
// ---------------------------------------------------------------------------
__global__ __launch_bounds__(256) void k_envg(
    const bf16* __restrict__ wenv, const float* __restrict__ Yb,
    const int* __restrict__ rowptr, int N, float* __restrict__ env) {
  int t = blockIdx.x * 256 + threadIdx.x;
  if (t >= N * 32) return;
  int n = t >> 5, m = t & 31;
  int j0 = rowptr[n], j1 = rowptr[n + 1];
  float a0 = 0.f, a1 = 0.f, a2 = 0.f, a3 = 0.f;
  for (int j = j0; j < j1; ++j) {
    float w0 = b2f(wenv[(long)j*64 + 2*m]);
    float w1 = b2f(wenv[(long)j*64 + 2*m + 1]);
    float4 y = *reinterpret_cast<const float4*>(&Yb[(long)j*4]);
    a0 += w0;
    a1 += w1 * y.y;
    a2 += w1 * y.z;
    a3 += w1 * y.w;
  }
  *reinterpret_cast<float4*>(&env[(long)n*128 + m*4]) = make_float4(a0, a1, a2, a3);
}

// ---------------------------------------------------------------------------
// node gather (CSR, slot-ordered) -> d_out
// ---------------------------------------------------------------------------
__global__ __launch_bounds__(256) void k_nodeg(
    const bf16* __restrict__ lat, const int* __restrict__ rowptr,
    int N, float* __restrict__ out) {
  int t = blockIdx.x * 256 + threadIdx.x;
  if (t >= N * 128) return;
  int n = t >> 7, j = t & 127;
  int j0 = rowptr[n], j1 = rowptr[n + 1];
  float s = 0.f;
  for (int q = j0; q < j1; ++q)
    s += b2f(lat[(long)q*128 + j]);
  out[t] = s * INV_SQRT_N;
}

// ---------------------------------------------------------------------------
// MFMA GEMM for the 40-wide two-body input (K padded 40->64 with zeros).
// ---------------------------------------------------------------------------
__global__ __launch_bounds__(256) void mgemm40(
    const bf16* __restrict__ A, const unsigned short* __restrict__ Wt,
    bf16* __restrict__ out, float scale, int E) {
  __shared__ __align__(16) unsigned short As[64 * 72];
  __shared__ __align__(16) unsigned short Bs[64 * 72];
  int tid = threadIdx.x;
  int lane = tid & 63, w = tid >> 6;
  int nl = lane & 15, quad = lane >> 4;
  long e0 = (long)blockIdx.x * 64;

  for (int i = tid; i < 512; i += 256) {
    int e = i >> 3, h = i & 7;
    short8 v = {0,0,0,0,0,0,0,0};
    long eg = e0 + e;
    if (h < 5 && eg < E) v = *(const short8*)(A + eg * 40 + h * 8);
    *(short8*)&As[e * 72 + h * 8] = v;
  }
  for (int i = tid; i < 512; i += 256) {
    int n = i >> 3, h = i & 7;
    short8 v = {0,0,0,0,0,0,0,0};
    if (h < 5) v = *(const short8*)(Wt + n * 40 + h * 8);
    *(short8*)&Bs[n * 72 + h * 8] = v;
  }
  __syncthreads();

  floatx4 acc[4];
  #pragma unroll
  for (int i = 0; i < 4; ++i) acc[i] = (floatx4){0.f,0.f,0.f,0.f};
  #pragma unroll
  for (int ks = 0; ks < 2; ++ks) {
    short8 af[4];
    #pragma unroll
    for (int et = 0; et < 4; ++et)
      af[et] = *(const short8*)&As[(et*16 + nl) * 72 + ks*32 + quad*8];
    short8 bv = *(const short8*)&Bs[(w*16 + nl) * 72 + ks*32 + quad*8];
    #pragma unroll
    for (int et = 0; et < 4; ++et) acc[et] = mfma16(af[et], bv, acc[et]);
  }
  #pragma unroll
  for (int et = 0; et < 4; ++et)
    #pragma unroll
    for (int r = 0; r < 4; ++r) {
      long eg = e0 + et*16 + quad*4 + r;
      if (eg >= E) continue;
      out[eg * 64 + w*16 + nl] = f2b(silu_f(acc[et][r] * scale));
    }
}

// ---------------------------------------------------------------------------
// MFMA single-layer GEMM: 64 edges x NOUT, A[e][K] bf16, Wt[n][K] bf16.
// ---------------------------------------------------------------------------
template<int K, int NOUT, int EPI>
__global__ __launch_bounds__(256) void mgemm(
    const bf16* __restrict__ A, const unsigned short* __restrict__ Wt,
    bf16* __restrict__ out1, bf16* __restrict__ out2, float scale, int E) {
  constexpr int KP = 40;
  constexpr int CT = NOUT / 64;
  __shared__ __align__(16) unsigned short As[64 * KP];
  __shared__ __align__(16) unsigned short Bs[NOUT * KP];
  int tid = threadIdx.x;
  int lane = tid & 63, w = tid >> 6;
  int nl = lane & 15, quad = lane >> 4;
  long e0 = (long)blockIdx.x * 64;

  floatx4 acc[4][CT];
  #pragma unroll
  for (int i = 0; i < 4; ++i)
    #pragma unroll
    for (int j = 0; j < CT; ++j) acc[i][j] = (floatx4){0.f,0.f,0.f,0.f};

  int ae = tid & 63, akh = tid >> 6;
  long aeg = e0 + ae;

  for (int k0 = 0; k0 < K; k0 += 32) {
    if (k0) __syncthreads();
    {
      short8 v = {0,0,0,0,0,0,0,0};
      if (aeg < E) v = *(const short8*)(A + aeg * (long)K + k0 + akh * 8);
      *(short8*)&As[ae * KP + akh * 8] = v;
    }
    if constexpr (NOUT == 128) {
      int j = tid >> 1, h = tid & 1;
      const short8* s = (const short8*)(Wt + (long)j * K + k0 + h * 16);
      *(short8*)&Bs[j * KP + h * 16]     = s[0];
      *(short8*)&Bs[j * KP + h * 16 + 8] = s[1];
    } else {
      int j = tid >> 2, h = tid & 3;
      *(short8*)&Bs[j * KP + h * 8] =
          *(const short8*)(Wt + (long)j * K + k0 + h * 8);
    }
    __syncthreads();
    short8 af[4], bv[CT];
    #pragma unroll
    for (int et = 0; et < 4; ++et)
      af[et] = *(const short8*)&As[(et*16 + nl) * KP + quad * 8];
    #pragma unroll
    for (int ct = 0; ct < CT; ++ct)
      bv[ct] = *(const short8*)&Bs[(w*CT*16 + ct*16 + nl) * KP + quad * 8];
    #pragma unroll
    for (int et = 0; et < 4; ++et)
      #pragma unroll
      for (int ct = 0; ct < CT; ++ct)
        acc[et][ct] = mfma16(af[et], bv[ct], acc[et][ct]);
  }

  #pragma unroll
  for (int et = 0; et < 4; ++et)
    #pragma unroll
    for (int ct = 0; ct < CT; ++ct)
      #pragma unroll
      for (int r = 0; r < 4; ++r) {
        long eg = e0 + et*16 + quad*4 + r;
        if (eg >= E) continue;
        int col = w*CT*16 + ct*16 + nl;
        float v = acc[et][ct][r] * scale;
        if constexpr (EPI == EPI_SPLIT) {
          if (col < 64) out1[eg * 64 + col] = f2b(v);
          else          out2[eg * 64 + (col - 64)] = f2b(v);
        } else { // EPI_STORE
          out1[eg * NOUT + col] = f2b(v);
        }
      }
}

// ---------------------------------------------------------------------------
// MFMA fused two-layer MLP: A(K) -> silu -> H(128, LDS bf16) -> @W1 -> epi
// ---------------------------------------------------------------------------
template<int K, int AMODE, int EPI>
__global__ __launch_bounds__(256) void mfused(
    const bf16* __restrict__ A, const bf16* __restrict__ A2,
    const unsigned short* __restrict__ W0t, const unsigned short* __restrict__ W1t,
    bf16* __restrict__ outb, const float* __restrict__ fcut,
    float scale0, float scale1, int E) {
  constexpr int KP = 40, HP = 136;
  __shared__ __align__(16) unsigned short As[64 * KP];
  __shared__ __align__(16) unsigned short Bs[128 * KP];
  __shared__ __align__(16) unsigned short Hs[64 * HP];
  int tid = threadIdx.x;
  int lane = tid & 63, w = tid >> 6;
  int nl = lane & 15, quad = lane >> 4;
  long e0 = (long)blockIdx.x * 64;

  floatx4 acc[4][2];
  #pragma unroll
  for (int i = 0; i < 4; ++i)
    #pragma unroll
    for (int j = 0; j < 2; ++j) acc[i][j] = (floatx4){0.f,0.f,0.f,0.f};

  int ae = tid & 63, akh = tid >> 6;
  long aeg = e0 + ae;
  int bj = tid >> 1, bh = tid & 1;

  for (int k0 = 0; k0 < K; k0 += 32) {
    if (k0) __syncthreads();
    {
      int kk = k0 + akh * 8;
      short8 v = {0,0,0,0,0,0,0,0};
      if (aeg < E) {
        const bf16* src;
        if constexpr (AMODE == AMODE_PLAIN) src = A + aeg * (long)K + kk;
        else src = (kk < 128) ? (A + aeg * 128 + kk) : (A2 + aeg * 64 + (kk - 128));
        v = *(const short8*)src;
      }
      *(short8*)&As[ae * KP + akh * 8] = v;
    }
    {
      const short8* s = (const short8*)(W0t + (long)bj * K + k0 + bh * 16);
      *(short8*)&Bs[bj * KP + bh * 16]     = s[0];
      *(short8*)&Bs[bj * KP + bh * 16 + 8] = s[1];
    }
    __syncthreads();
    short8 af[4], bv[2];
    #pragma unroll
    for (int et = 0; et < 4; ++et)
      af[et] = *(const short8*)&As[(et*16 + nl) * KP + quad * 8];
    #pragma unroll
    for (int ct = 0; ct < 2; ++ct)
      bv[ct] = *(const short8*)&Bs[(w*32 + ct*16 + nl) * KP + quad * 8];
    #pragma unroll
    for (int et = 0; et < 4; ++et)
      #pragma unroll
      for (int ct = 0; ct < 2; ++ct)
        acc[et][ct] = mfma16(af[et], bv[ct], acc[et][ct]);
  }

  #pragma unroll
  for (int et = 0; et < 4; ++et)
    #pragma unroll
    for (int ct = 0; ct < 2; ++ct)
      #pragma unroll
      for (int r = 0; r < 4; ++r) {
        int el = et*16 + quad*4 + r;
        int h  = w*32 + ct*16 + nl;
        Hs[el * HP + h] = f2bu(silu_f(acc[et][ct][r] * scale0));
      }
  #pragma unroll
  for (int i = 0; i < 4; ++i)
    #pragma unroll
    for (int j = 0; j < 2; ++j) acc[i][j] = (floatx4){0.f,0.f,0.f,0.f};

  for (int k0 = 0; k0 < 128; k0 += 32) {
    __syncthreads();
    {
      const short8* s = (const short8*)(W1t + (long)bj * 128 + k0 + bh * 16);
      *(short8*)&Bs[bj * KP + bh * 16]     = s[0];
      *(short8*)&Bs[bj * KP + bh * 16 + 8] = s[1];
    }
    __syncthreads();
    short8 af[4], bv[2];
    #pragma unroll
    for (int et = 0; et < 4; ++et)
      af[et] = *(const short8*)&Hs[(et*16 + nl) * HP + k0 + quad * 8];
    #pragma unroll
    for (int ct = 0; ct < 2; ++ct)
      bv[ct] = *(const short8*)&Bs[(w*32 + ct*16 + nl) * KP + quad * 8];
    #pragma unroll
    for (int et = 0; et < 4; ++et)
      #pragma unroll
      for (int ct = 0; ct < 2; ++ct)
        acc[et][ct] = mfma16(af[et], bv[ct], acc[et][ct]);
  }

  #pragma unroll
  for (int et = 0; et < 4; ++et)
    #pragma unroll
    for (int ct = 0; ct < 2; ++ct)
      #pragma unroll
      for (int r = 0; r < 4; ++r) {
        long eg = e0 + et*16 + quad*4 + r;
        if (eg >= E) continue;
        int col = w*32 + ct*16 + nl;
        float fc = fcut[eg];
        float v = acc[et][ct][r] * scale1 * fc;
        if constexpr (EPI == EPI_FCUT) {
          outb[eg * 128 + col] = f2b(v);
        } else { // EPI_RESID
          long idx = eg * 128 + col;
          outb[idx] = f2b(C_OLD * b2f(outb[idx]) + C_NEW * v);
        }
      }
}

// ---------------------------------------------------------------------------
// products -> scal0 = [p0 | p1]  (slot-ordered: env reads L1-local)
// ---------------------------------------------------------------------------
__global__ __launch_bounds__(256) void k_prod(
    const bf16* __restrict__ wedge, const float* __restrict__ env,
    const float* __restrict__ Yb, const int* __restrict__ cent, int E,
    bf16* __restrict__ scal) {
  long t = (long)blockIdx.x * 256 + threadIdx.x;
  if (t >= (long)E * 32) return;
  long e = t >> 5;
  int m = (int)(t & 31);
  int c = cent[e];
  float w0 = b2f(wedge[e*64 + 2*m]), w1 = b2f(wedge[e*64 + 2*m + 1]);
  const float* ep = env + (long)c*128 + m*4;
  float es  = ep[0] * INV_SQRT_N;
  float evx = ep[1] * INV_SQRT_N, evy = ep[2] * INV_SQRT_N, evz = ep[3] * INV_SQRT_N;
  float y1 = Yb[e*4+1], y2 = Yb[e*4+2], y3 = Yb[e*4+3];
  float fvx = w1*y1, fvy = w1*y2, fvz = w1*y3;
  scal[e*64 + m]      = f2b(w0 * es);
  scal[e*64 + 32 + m] = f2b((fvx*evx + fvy*evy + fvz*evz) * INV_SQRT3);
}

// ---------------------------------------------------------------------------
// MFMA mix (slot-ordered): products -> LDS, 4 wave-jobs, combine env1 -> scal1
// ---------------------------------------------------------------------------
__global__ __launch_bounds__(256) void k_mix2(
    const bf16* __restrict__ wedge, const float* __restrict__ env,
    const float* __restrict__ env1, const float* __restrict__ Yb,
    const int* __restrict__ cent, const unsigned short* __restrict__ Wm,
    int E, bf16* __restrict__ scal) {
  constexpr int PP = 360;
  constexpr int RP = 132;
  __shared__ __align__(16) unsigned char SB[64 * PP * 2];
  __shared__ __align__(16) unsigned short Wl[32 * 160];
  unsigned short* P = (unsigned short*)SB;
  float* R = (float*)SB;
  int tid = threadIdx.x;
  int lane = tid & 63, w = tid >> 6;
  int nl = lane & 15, quad = lane >> 4;
  long e0 = (long)blockIdx.x * 64;

  for (int i = tid; i < 640; i += 256)
    *(short8*)&Wl[i * 8] = *(const short8*)(Wm + i * 8);

  int m = tid & 31;
  #pragma unroll
  for (int it = 0; it < 8; ++it) {
    int el = (tid >> 5) + it * 8;
    long e = e0 + el;
    if (e < E) {
      int c = cent[e];
      float w0 = b2f(wedge[e*64 + 2*m]), w1 = b2f(wedge[e*64 + 2*m + 1]);
      float4 ev4 = *(const float4*)(env + (long)c*128 + m*4);
      float4 y   = *(const float4*)(Yb + e*4);
      float es  = ev4.x * INV_SQRT_N;
      float evx = ev4.y * INV_SQRT_N, evy = ev4.z * INV_SQRT_N, evz = ev4.w * INV_SQRT_N;
      float fvx = w1*y.y, fvy = w1*y.z, fvz = w1*y.w;
      unsigned short* p = P + el * PP;
      p[m]       = f2bu(w0 * es);
      p[32 + m]  = f2bu((fvx*evx + fvy*evy + fvz*evz) * INV_SQRT3);
      p[64 + m]  = f2bu(w0 * evx);
      p[96 + m]  = f2bu(fvx * es);
      p[128 + m] = f2bu((fvy*evz - fvz*evy) * INV_SQRT2);
      p[160 + m] = f2bu(w0 * evy);
      p[192 + m] = f2bu(fvy * es);
      p[224 + m] = f2bu((fvz*evx - fvx*evz) * INV_SQRT2);
      p[256 + m] = f2bu(w0 * evz);
      p[288 + m] = f2bu(fvz * es);
      p[320 + m] = f2bu((fvx*evy - fvy*evx) * INV_SQRT2);
    } else {
      unsigned short* p = P + el * PP;
      #pragma unroll
      for (int q = 0; q < 11; ++q) p[q*32 + m] = 0;
    }
  }
  __syncthreads();

  floatx4 acc[4][2];
  #pragma unroll
  for (int i = 0; i < 4; ++i)
    #pragma unroll
    for (int j = 0; j < 2; ++j) acc[i][j] = (floatx4){0.f,0.f,0.f,0.f};
  int pbase  = (w == 0) ? 0 : 64 + (w - 1) * 96;
  int wkbase = (w == 0) ? 0 : 64;
  int ksteps = (w == 0) ? 2 : 3;
  for (int ks = 0; ks < ksteps; ++ks) {
    short8 af[4], bv[2];
    #pragma unroll
    for (int et = 0; et < 4; ++et)
      af[et] = *(const short8*)&P[(et*16 + nl) * PP + pbase + ks*32 + quad*8];
    #pragma unroll
    for (int ct = 0; ct < 2; ++ct)
      bv[ct] = *(const short8*)&Wl[(ct*16 + nl) * 160 + wkbase + ks*32 + quad*8];
    #pragma unroll
    for (int et = 0; et < 4; ++et)
      #pragma unroll
      for (int ct = 0; ct < 2; ++ct)
        acc[et][ct] = mfma16(af[et], bv[ct], acc[et][ct]);
  }
  __syncthreads();

  #pragma unroll
  for (int et = 0; et < 4; ++et)
    #pragma unroll
    for (int ct = 0; ct < 2; ++ct)
      #pragma unroll
      for (int r = 0; r < 4; ++r) {
        int el = et*16 + quad*4 + r;
        R[el * RP + w*32 + ct*16 + nl] = acc[et][ct][r];
      }
  __syncthreads();

  #pragma unroll
  for (int it = 0; it < 8; ++it) {
    int el = (tid >> 5) + it * 8;
    long e = e0 + el;
    if (e >= E) continue;
    int o = m;
    int c = cent[e];
    float4 e1 = *(const float4*)(env1 + (long)c*128 + o*4);
    float sr = R[el * RP + o];
    float vx = R[el * RP + 32 + o];
    float vy = R[el * RP + 64 + o];
    float vz = R[el * RP + 96 + o];
    float q0 = sr * 0.125f * (e1.x * INV_SQRT_N);
    float q1 = (vx*e1.y + vy*e1.z + vz*e1.w) *
               (0.10206207261596577f * INV_SQRT_N * INV_SQRT3);
    scal[e*64 + o]      = f2b(q0);
    scal[e*64 + 32 + o] = f2b(q1);
  }
}

// ---------------------------------------------------------------------------
extern "C" void kernel_launch(void* const* d_in, const int* in_sizes, int n_in,
                              void* d_out, int out_size, void* d_ws, size_t ws_size,
                              hipStream_t stream) {
  const float* coords = (const float*)d_in[0];
  const float* nattr  = (const float*)d_in[1];
  const int*   eidx   = (const int*)d_in[2];
  const float* W2b0   = (const float*)d_in[3];
  const float* W2b1   = (const float*)d_in[4];
  const float* W2b2   = (const float*)d_in[5];
  const float* Wenv0  = (const float*)d_in[6];
  const float* Wlat0  = (const float*)d_in[7];
  const float* Wlat1  = (const float*)d_in[8];
  const float* Ws0    = (const float*)d_in[9];
  const float* Wv0    = (const float*)d_in[10];
  const float* Wenv1  = (const float*)d_in[11];
  const float* Wfin0  = (const float*)d_in[12];
  const float* Wfin1  = (const float*)d_in[13];
  float* out = (float*)d_out;
  int E = in_sizes[2] / 2;     // 320000
  int N = in_sizes[0] / 3;     // 10000

  // workspace carve (~183 MB)
  float* fcut   = (float*)d_ws;                    // E
  float* Yb     = fcut + (size_t)E;                // 4E
  float* env    = Yb + (size_t)E*4;                // 128N
  float* env1   = env + (size_t)N*128;             // 128N
  int*   deg    = (int*)(env1 + (size_t)N*128);    // N
  int*   rowptr = deg + N;                         // N+8
  int*   cursor = rowptr + (N + 8);                // N
  int*   eord   = cursor + N;                      // E
  int*   cent   = eord + E;                        // E
  bf16*  b64    = (bf16*)(cent + E);               // 64E (h64, then wedge)
  bf16*  lat    = b64 + (size_t)E*64;              // 128E
  bf16*  S      = lat + (size_t)E*128;             // 64E (a40/wenv/scal0/wenv1/scal1)
  unsigned short* W2b1t  = (unsigned short*)(S + (size_t)E*64);  // 128x64
  unsigned short* W2b2t  = W2b1t + 128*64;
  unsigned short* Wenv0t = W2b2t + 128*128;
  unsigned short* Wlat0t = Wenv0t + 128*128;
  unsigned short* Wlat1t = Wlat0t + 128*192;
  unsigned short* Wenv1t = Wlat1t + 128*128;
  unsigned short* Wfin0t = Wenv1t + 64*128;
  unsigned short* Wfin1t = Wfin0t + 128*192;
  unsigned short* W2b0t  = Wfin1t + 128*128;
  unsigned short* Wmixt  = W2b0t + 64*40;

  hipMemsetAsync(deg, 0, (size_t)N * sizeof(int), stream);

  dim3 blk(256);
  const float s40  = 0.15811388300841897f;  // 1/sqrt(40)
  const float s64  = 0.125f;
  const float s128 = 0.08838834764831845f;
  const float s192 = 0.07216878364870323f;
  int gB = (E + 63) / 64;
  int gE = (E + 255) / 256;

  // CSR build, then slot-ordered geometry; merged weight prep
  k_deg<<<gE, blk, 0, stream>>>(eidx, E, deg);
  k_scan<<<1, 1024, 0, stream>>>(deg, N, rowptr, cursor);
  k_fill<<<gE, blk, 0, stream>>>(eidx, E, cursor, eord, cent);
  k_geom<<<gE, blk, 0, stream>>>(coords, nattr, eidx, eord, E, fcut, Yb, S /*a40*/);
  k_wprep_all<<<dim3(542), blk, 0, stream>>>(
      W2b0, W2b1, W2b2, Wenv0, Wlat0, Wlat1, Wenv1, Wfin0, Wfin1, Ws0, Wv0,
      W2b0t, W2b1t, W2b2t, Wenv0t, Wlat0t, Wlat1t, Wenv1t, Wfin0t, Wfin1t, Wmixt);

  // two-body MLP
  mgemm40<<<gB, blk, 0, stream>>>(S /*a40*/, W2b0t, b64, s40, E);
  mfused<64,AMODE_PLAIN,EPI_FCUT><<<gB, blk, 0, stream>>>(
      b64, nullptr, W2b1t, W2b2t, lat, fcut, s64, s128, E);

  // Wenv0: w_edge -> b64, w_env -> S
  mgemm<128,128,EPI_SPLIT><<<gB, blk, 0, stream>>>(
      lat, Wenv0t, b64, S /*wenv*/, s128, E);

  // env = CSR gather (sequential)
  k_envg<<<dim3((N*32 + 255) / 256), blk, 0, stream>>>(
      S /*wenv*/, Yb, rowptr, N, env);

  // products -> scal0
  k_prod<<<dim3((int)(((long)E*32 + 255) / 256)), blk, 0, stream>>>(
      b64, env, Yb, cent, E, S /*scal0*/);

  // latent MLP + residual
  mfused<192,AMODE_CONCAT,EPI_RESID><<<gB, blk, 0, stream>>>(
      lat, S /*scal0*/, Wlat0t, Wlat1t, lat, fcut, s192, s128, E);

  // Wenv1 -> wenv1
  mgemm<128,64,EPI_STORE><<<gB, blk, 0, stream>>>(
      lat, Wenv1t, S /*wenv1*/, nullptr, s128, E);

  // env1 = CSR gather (sequential)
  k_envg<<<dim3((N*32 + 255) / 256), blk, 0, stream>>>(
      S /*wenv1*/, Yb, rowptr, N, env1);

  // MFMA mix -> scal1
  k_mix2<<<gB, blk, 0, stream>>>(
      b64, env, env1, Yb, cent, Wmixt, E, S /*scal1*/);

  // final MLP + residual
  mfused<192,AMODE_CONCAT,EPI_RESID><<<gB, blk, 0, stream>>>(
      lat, S /*scal1*/, Wfin0t, Wfin1t, lat, fcut, s192, s128, E);

  // node segment-sum (sequential) -> d_out
  k_nodeg<<<dim3((N*128 + 255) / 256), blk, 0, stream>>>(
      lat, rowptr, N, out);
}